// Round 5
// baseline (169.500 us; speedup 1.0000x reference)
//
#include <hip/hip_runtime.h>
#include <hip/hip_bf16.h>

// MambaBlock: H=256, S=16, B=2, N=8192. fp32 I/O.
// No decay (A_log unused) => SSM state is a pure prefix-sum: chunk-parallel.
// Round 5: 512-thread blocks (16 waves/CU), LDS-staged A operand with deep
// coalesced loads, s-split chunk-sum/scan. 5 kernels.

#define HD 256
#define SD 16
#define NSEQ 8192
#define NBATCH 2
#define BN (NBATCH * NSEQ)      // 16384 rows
#define CHUNK 32
#define NCHUNK (NSEQ / CHUNK)   // 256
#define NGRP 16
#define GSZ (NCHUNK / NGRP)     // 16
#define LN_EPS 1e-5f

#define NIW (2 * HD * HD)       // 131,072 in_w
#define NXP (48 * HD)           // 12,288  xp_w padded (src 33*256=8448)
#define NOW (HD * HD)           // 65,536  out_w

typedef __hip_bfloat16 bf16;
typedef __attribute__((ext_vector_type(8))) short bf16x8;
typedef __attribute__((ext_vector_type(4))) short short4v;
typedef __attribute__((ext_vector_type(4))) float f32x4;

__device__ __forceinline__ float b2f(bf16 v) { return __bfloat162float(v); }
__device__ __forceinline__ short f2bs(float f) {
  union { bf16 b; short s; } u;
  u.b = __float2bfloat16(f);
  return u.s;
}
__device__ __forceinline__ bf16x8 cvt_frag(const float* p) {
  bf16x8 r;
#pragma unroll
  for (int j = 0; j < 8; ++j) r[j] = f2bs(p[j]);
  return r;
}
__device__ __forceinline__ float softplus_f(float a) {
  return (a > 20.f) ? a : __logf(1.f + __expf(a));
}

// ---------------------------------------------------------------------------
// K0: weight conversions fp32->bf16 (xp_w zero-padded 33->48 rows).
// ---------------------------------------------------------------------------
__global__ __launch_bounds__(256) void k0_weights(
    const float* __restrict__ in_w, const float* __restrict__ xp_w,
    const float* __restrict__ out_w, bf16* __restrict__ wbin,
    bf16* __restrict__ wbxp, bf16* __restrict__ wbout)
{
  const int base = (blockIdx.x * 256 + threadIdx.x) * 4;
  if (base < NIW) {
    f32x4 v = *(const f32x4*)(in_w + base);
    *(short4v*)((short*)wbin + base) =
        short4v{f2bs(v[0]), f2bs(v[1]), f2bs(v[2]), f2bs(v[3])};
  } else if (base < NIW + NXP) {
    const int off = base - NIW;
    short4v s;
    if (off < 33 * HD) {
      f32x4 v = *(const f32x4*)(xp_w + off);
      s = short4v{f2bs(v[0]), f2bs(v[1]), f2bs(v[2]), f2bs(v[3])};
    } else {
      s = short4v{0, 0, 0, 0};
    }
    *(short4v*)((short*)wbxp + off) = s;
  } else if (base < NIW + NXP + NOW) {
    const int off = base - NIW - NXP;
    f32x4 v = *(const f32x4*)(out_w + off);
    *(short4v*)((short*)wbout + off) =
        short4v{f2bs(v[0]), f2bs(v[1]), f2bs(v[2]), f2bs(v[3])};
  }
}

// ---------------------------------------------------------------------------
// K1F: per 32-row chunk (512 threads, 8 waves):
//   stage x-tile -> LDS (coalesced, deep outstanding loads)
//   [x_inner|z] = x @ in_w^T + in_b   (8 wave-tiles 16x128, A from LDS)
//   dbc = x_inner @ xp_w^T + xp_b     (waves 0,1 from LDS)
//   Mc[c][s][h] chunk-sum             (512 thr: (h, s-half))
//   xib, zb bf16 out (coalesced vec8)
// ---------------------------------------------------------------------------
__global__ __launch_bounds__(512) void k1f_in_xp_sum(
    const float* __restrict__ x, const bf16* __restrict__ wbin,
    const float* __restrict__ in_b, const bf16* __restrict__ wbxp,
    const float* __restrict__ xp_b, const float* __restrict__ dt_w,
    const float* __restrict__ dt_b, bf16* __restrict__ xib,
    bf16* __restrict__ zb, float* __restrict__ dbc, float* __restrict__ Mc)
{
  __shared__ float xt[32][260];   // 33.3 KB (x, then x_inner)
  __shared__ float zt[32][260];   // 33.3 KB (z)
  __shared__ float sdbc[32][33];  // 4.2 KB
  const int tid = threadIdx.x;
  const int wave = tid >> 6, lane = tid & 63, q = lane >> 4, l16 = lane & 15;
  const int R0 = blockIdx.x * CHUNK;

  // ---- stage x tile (32 x 256 f32), coalesced ----
  {
    const int row = tid >> 4;            // 0..31
    const int c0 = (tid & 15) * 16;      // 0..240
    const float* src = x + (size_t)(R0 + row) * HD + c0;
#pragma unroll
    for (int j = 0; j < 4; ++j)
      *(f32x4*)&xt[row][c0 + j * 4] = *(const f32x4*)(src + j * 4);
  }
  __syncthreads();

  // ---- main GEMM: wave tile 16 rows x 128 cols ----
  const int mrow = (wave & 1) * 16;
  const int colBase = (wave >> 1) * 128;   // 0..384
  f32x4 acc[8] = {};
  {
    const bf16* bp = wbin + (size_t)(colBase + l16) * HD + q * 8;
#pragma unroll
    for (int k = 0; k < HD; k += 32) {
      bf16x8 af = cvt_frag(&xt[mrow + l16][k + q * 8]);
#pragma unroll
      for (int t = 0; t < 8; ++t) {
        bf16x8 bfr = *(const bf16x8*)(bp + (size_t)t * 16 * HD + k);
        acc[t] = __builtin_amdgcn_mfma_f32_16x16x32_bf16(af, bfr, acc[t], 0, 0, 0);
      }
    }
  }
  __syncthreads();   // all xt A-reads complete before overwrite

  // ---- epilogue: x_inner -> xt (waves 0-3), z -> zt (waves 4-7) ----
  {
    float (*dst)[260] = (wave < 4) ? xt : zt;
    const int cb = (wave < 4) ? colBase : (colBase - 256);
#pragma unroll
    for (int t = 0; t < 8; ++t) {
      const int gcol = colBase + t * 16 + l16;
      const float bias = in_b[gcol];
#pragma unroll
      for (int r = 0; r < 4; ++r)
        dst[mrow + q * 4 + r][cb + t * 16 + l16] = acc[t][r] + bias;
    }
  }
  __syncthreads();

  // ---- xib/zb copy-out (all threads) ----
  {
    const int row = tid >> 4;
    const int c0 = (tid & 15) * 16;
    bf16* xd = xib + (size_t)(R0 + row) * HD + c0;
    bf16* zd = zb + (size_t)(R0 + row) * HD + c0;
    *(bf16x8*)xd = cvt_frag(&xt[row][c0]);
    *(bf16x8*)(xd + 8) = cvt_frag(&xt[row][c0 + 8]);
    *(bf16x8*)zd = cvt_frag(&zt[row][c0]);
    *(bf16x8*)(zd + 8) = cvt_frag(&zt[row][c0 + 8]);
  }

  // ---- xp-GEMM (waves 0,1): 16 rows x 48 cols each ----
  if (wave < 2) {
    f32x4 pacc[3] = {};
    const bf16* pb = wbxp + (size_t)l16 * HD + q * 8;
#pragma unroll
    for (int k = 0; k < HD; k += 32) {
      bf16x8 af = cvt_frag(&xt[wave * 16 + l16][k + q * 8]);
#pragma unroll
      for (int t = 0; t < 3; ++t) {
        bf16x8 bfr = *(const bf16x8*)(pb + (size_t)t * 16 * HD + k);
        pacc[t] = __builtin_amdgcn_mfma_f32_16x16x32_bf16(af, bfr, pacc[t], 0, 0, 0);
      }
    }
#pragma unroll
    for (int t = 0; t < 3; ++t) {
      const int col = t * 16 + l16;
      if (col < 33) {
        const float bias = xp_b[col];
#pragma unroll
        for (int r = 0; r < 4; ++r)
          sdbc[wave * 16 + q * 4 + r][col] = pacc[t][r] + bias;
      }
    }
  }
  __syncthreads();

  // ---- dbc coalesced copy + chunk-sum ((h, s-half) split) ----
  {
    const float* sflat = &sdbc[0][0];
    for (int idx = tid; idx < CHUNK * 33; idx += 512)
      dbc[(size_t)R0 * 33 + idx] = sflat[idx];
  }
  {
    const int h = tid & 255;
    const int sh = tid >> 8;             // 0/1
    const float dtw = dt_w[h], dtb = dt_b[h];
    float st[8] = {};
#pragma unroll
    for (int n = 0; n < CHUNK; ++n) {
      const float xv = xt[n][h];
      const float dt = softplus_f(sdbc[n][0] * dtw + dtb);
      const float u = xv * dt;
#pragma unroll
      for (int s = 0; s < 8; ++s) st[s] += u * sdbc[n][1 + sh * 8 + s];
    }
    const int b = R0 >> 13, c = (R0 & (NSEQ - 1)) >> 5;
    float* mp = Mc + ((size_t)(b * NCHUNK + c)) * 4096 + (sh * 8) * HD + h;
#pragma unroll
    for (int s = 0; s < 8; ++s) mp[s * HD] = st[s];   // [s][h] layout
  }
}

// ---------------------------------------------------------------------------
// K4a: exclusive prefix of Mc within each group of GSZ chunks (in-place);
// group totals -> Gs. Flat over the 4096 hs slots per chunk.
// ---------------------------------------------------------------------------
__global__ __launch_bounds__(256) void k4a_prefix_local(
    float* __restrict__ Mc, float* __restrict__ Gs)
{
  const int tid = blockIdx.x * 256 + threadIdx.x;   // 131072
  const int b = tid >> 16;
  const int g = (tid >> 12) & (NGRP - 1);
  const int hs = tid & 4095;
  float run = 0.f;
#pragma unroll
  for (int i = 0; i < GSZ; ++i) {
    const size_t idx = ((size_t)(b * NCHUNK + g * GSZ + i)) * 4096 + hs;
    const float v = Mc[idx];
    Mc[idx] = run;
    run += v;
  }
  Gs[((size_t)(b * NGRP + g)) * 4096 + hs] = run;
}

// ---------------------------------------------------------------------------
// K4b: exclusive prefix over the NGRP group totals (in-place).
// ---------------------------------------------------------------------------
__global__ __launch_bounds__(256) void k4b_prefix_groups(float* __restrict__ Gs)
{
  const int tid = blockIdx.x * 256 + threadIdx.x;   // 8192
  const int b = tid >> 12;
  const int hs = tid & 4095;
  float run = 0.f;
#pragma unroll
  for (int g = 0; g < NGRP; ++g) {
    const size_t idx = ((size_t)(b * NGRP + g)) * 4096 + hs;
    const float v = Gs[idx];
    Gs[idx] = run;
    run += v;
  }
}

// ---------------------------------------------------------------------------
// K56: seeded scan (s-split) -> y -> out GEMM + residual + LayerNorm.
// Block = 1 chunk (32 rows), 512 threads / 8 waves.
// ---------------------------------------------------------------------------
__global__ __launch_bounds__(512) void k56_scan_out_ln(
    const bf16* __restrict__ xib, const bf16* __restrict__ zb,
    const float* __restrict__ dbc, const float* __restrict__ dt_w,
    const float* __restrict__ dt_b, const float* __restrict__ Dv,
    const float* __restrict__ Mc, const float* __restrict__ Gs,
    const bf16* __restrict__ wbout, const float* __restrict__ out_b,
    const float* __restrict__ x, const float* __restrict__ ln_g,
    const float* __restrict__ ln_b, float* __restrict__ out)
{
  __shared__ float sdbc[CHUNK][33];   // 4.2 KB
  __shared__ float yt[32][260];       // 33.3 KB (y half0, then gated y)
  __shared__ float pt[32][260];       // 33.3 KB (y half1, then r)
  const int tid = threadIdx.x;
  const int wave = tid >> 6, lane = tid & 63, q = lane >> 4, l16 = lane & 15;
  const int R0 = blockIdx.x * CHUNK;
  const int b = R0 >> 13;
  const int cchunk = (R0 & (NSEQ - 1)) >> 5;

  for (int idx = tid; idx < CHUNK * 33; idx += 512) {
    const int n = idx / 33, j = idx - n * 33;
    sdbc[n][j] = dbc[(size_t)(R0 + n) * 33 + j];
  }
  __syncthreads();

  // ---- scan halves: thread = (h, s-half) ----
  {
    const int h = tid & 255;
    const int sh = tid >> 8;
    const float dtw = dt_w[h], dtb = dt_b[h];
    const float dv = Dv[h];
    float st[8];
    const float* mp = Mc + ((size_t)(b * NCHUNK + cchunk)) * 4096 + sh * 8 * HD + h;
    const float* gp = Gs + ((size_t)(b * NGRP + cchunk / GSZ)) * 4096 + sh * 8 * HD + h;
#pragma unroll
    for (int s = 0; s < 8; ++s) st[s] = mp[s * HD] + gp[s * HD];
    float (*dst)[260] = (sh == 0) ? yt : pt;
    for (int n = 0; n < CHUNK; ++n) {
      const float xv = b2f(xib[(size_t)(R0 + n) * HD + h]);
      const float dt = softplus_f(sdbc[n][0] * dtw + dtb);
      const float u = xv * dt;
      float y = (sh == 0) ? dv * xv : 0.f;
#pragma unroll
      for (int s = 0; s < 8; ++s) {
        st[s] += u * sdbc[n][1 + sh * 8 + s];
        y += st[s] * sdbc[n][17 + sh * 8 + s];
      }
      dst[n][h] = y;
    }
  }
  __syncthreads();

  // ---- combine halves + silu(z) gate -> yt ----
  {
    const int h = tid & 255;
    const int r2 = tid >> 8;
#pragma unroll
    for (int j = 0; j < 16; ++j) {
      const int row = r2 * 16 + j;
      const float zv = b2f(zb[(size_t)(R0 + row) * HD + h]);
      const float sig = 1.f / (1.f + __expf(-zv));
      yt[row][h] = (yt[row][h] + pt[row][h]) * zv * sig;
    }
  }
  __syncthreads();

  // ---- out GEMM: wave tile 16 rows x 64 cols ----
  const int mrow = (wave & 1) * 16;
  const int colBase = (wave >> 1) * 64;
  f32x4 acc[4] = {};
  {
    const bf16* bp = wbout + (size_t)(colBase + l16) * HD + q * 8;
#pragma unroll
    for (int k = 0; k < HD; k += 32) {
      bf16x8 af = cvt_frag(&yt[mrow + l16][k + q * 8]);
#pragma unroll
      for (int t = 0; t < 4; ++t) {
        bf16x8 bfr = *(const bf16x8*)(bp + (size_t)t * 16 * HD + k);
        acc[t] = __builtin_amdgcn_mfma_f32_16x16x32_bf16(af, bfr, acc[t], 0, 0, 0);
      }
    }
  }
  __syncthreads();   // yt reads done

  // ---- r = acc + out_b + residual -> pt ----
#pragma unroll
  for (int t = 0; t < 4; ++t) {
    const int col = colBase + t * 16 + l16;
    const float bias = out_b[col];
#pragma unroll
    for (int r = 0; r < 4; ++r) {
      const int row = mrow + q * 4 + r;
      pt[row][col] = acc[t][r] + bias + x[(size_t)(R0 + row) * HD + col];
    }
  }
  __syncthreads();

  // ---- LayerNorm: wave handles rows wave*4 .. wave*4+3 ----
#pragma unroll
  for (int rr = 0; rr < 4; ++rr) {
    const int row = wave * 4 + rr;
    float p = 0.f;
#pragma unroll
    for (int j = 0; j < 4; ++j) p += pt[row][lane + 64 * j];
#pragma unroll
    for (int off = 32; off > 0; off >>= 1) p += __shfl_xor(p, off);
    const float mu = p * (1.f / 256.f);
    float v2 = 0.f;
#pragma unroll
    for (int j = 0; j < 4; ++j) {
      const float d = pt[row][lane + 64 * j] - mu;
      v2 += d * d;
    }
#pragma unroll
    for (int off = 32; off > 0; off >>= 1) v2 += __shfl_xor(v2, off);
    const float rstd = rsqrtf(v2 * (1.f / 256.f) + LN_EPS);
    const size_t base = (size_t)(R0 + row) * HD;
#pragma unroll
    for (int j = 0; j < 4; ++j) {
      const int cc = lane + 64 * j;
      out[base + cc] = ln_g[cc] * (pt[row][cc] - mu) * rstd + ln_b[cc];
    }
  }
}

// ---------------------------------------------------------------------------
extern "C" void kernel_launch(void* const* d_in, const int* in_sizes, int n_in,
                              void* d_out, int out_size, void* d_ws, size_t ws_size,
                              hipStream_t stream)
{
  const float* x     = (const float*)d_in[0];
  const float* in_w  = (const float*)d_in[1];
  const float* in_b  = (const float*)d_in[2];
  const float* xp_w  = (const float*)d_in[3];
  const float* xp_b  = (const float*)d_in[4];
  const float* dt_w  = (const float*)d_in[5];
  const float* dt_b  = (const float*)d_in[6];
  // d_in[7] = A_log — unused by the reference
  const float* Dv    = (const float*)d_in[8];
  const float* out_w = (const float*)d_in[9];
  const float* out_b = (const float*)d_in[10];
  const float* ln_g  = (const float*)d_in[11];
  const float* ln_b  = (const float*)d_in[12];

  char* ws = (char*)d_ws;
  bf16*  xib   = (bf16*)(ws);               // 8,388,608 B
  bf16*  zb    = (bf16*)(ws +  8388608);    // 8,388,608 B
  float* dbc   = (float*)(ws + 16777216);   // 2,162,688 B
  float* Mc    = (float*)(ws + 18939904);   // 8,388,608 B
  float* Gs    = (float*)(ws + 27328512);   //   524,288 B
  bf16*  wbin  = (bf16*)(ws + 27852800);    //   262,144 B
  bf16*  wbxp  = (bf16*)(ws + 28114944);    //    24,576 B
  bf16*  wbout = (bf16*)(ws + 28139520);    //   131,072 B
  float* out   = (float*)d_out;

  hipLaunchKernelGGL(k0_weights, dim3((NIW + NXP + NOW) / 1024), dim3(256),
                     0, stream, in_w, xp_w, out_w, wbin, wbxp, wbout);
  hipLaunchKernelGGL(k1f_in_xp_sum, dim3(BN / CHUNK), dim3(512), 0, stream,
                     x, wbin, in_b, wbxp, xp_b, dt_w, dt_b,
                     xib, zb, dbc, Mc);
  hipLaunchKernelGGL(k4a_prefix_local, dim3(NBATCH * NGRP * 4096 / 256),
                     dim3(256), 0, stream, Mc, Gs);
  hipLaunchKernelGGL(k4b_prefix_groups, dim3(NBATCH * 4096 / 256), dim3(256),
                     0, stream, Gs);
  hipLaunchKernelGGL(k56_scan_out_ln, dim3(BN / CHUNK), dim3(512), 0, stream,
                     xib, zb, dbc, dt_w, dt_b, Dv, Mc, Gs,
                     wbout, out_b, x, ln_g, ln_b, out);
}

// Round 6
// 150.318 us; speedup vs baseline: 1.1276x; 1.1276x over previous
//
#include <hip/hip_runtime.h>
#include <hip/hip_bf16.h>

// MambaBlock: H=256, S=16, B=2, N=8192. fp32 I/O.
// No decay (A_log unused) => SSM state is a pure prefix-sum: chunk-parallel.
// Round 6: k1 as classic LDS-tiled GEMM (128x128 tile, 4:1 MFMA:load),
// k2 all-LDS xp-GEMM + chunk-sum, k56 GEMM with 2:1 ratio. 6 kernels.

#define HD 256
#define SD 16
#define NSEQ 8192
#define NBATCH 2
#define BN (NBATCH * NSEQ)      // 16384 rows
#define CHUNK 32
#define NCHUNK (NSEQ / CHUNK)   // 256
#define NGRP 16
#define GSZ (NCHUNK / NGRP)     // 16
#define LN_EPS 1e-5f

#define NX  (BN * HD)           // 4,194,304 x elements
#define NIW (2 * HD * HD)       // 131,072  in_w
#define NXP (48 * HD)           // 12,288   xp_w padded (src 33*256=8448)
#define NOW (HD * HD)           // 65,536   out_w

typedef __hip_bfloat16 bf16;
typedef __attribute__((ext_vector_type(8))) short bf16x8;
typedef __attribute__((ext_vector_type(4))) short short4v;
typedef __attribute__((ext_vector_type(4))) float f32x4;

__device__ __forceinline__ float b2f(bf16 v) { return __bfloat162float(v); }
__device__ __forceinline__ short f2bs(float f) {
  union { bf16 b; short s; } u;
  u.b = __float2bfloat16(f);
  return u.s;
}
__device__ __forceinline__ bf16x8 cvt_frag(const float* p) {
  bf16x8 r;
#pragma unroll
  for (int j = 0; j < 8; ++j) r[j] = f2bs(p[j]);
  return r;
}
__device__ __forceinline__ float softplus_f(float a) {
  return (a > 20.f) ? a : __logf(1.f + __expf(a));
}

// ---------------------------------------------------------------------------
// K0: fp32->bf16: x->xb, in_w->wbin, xp_w->wbxp (zero-pad 33->48), out_w->wbout
// ---------------------------------------------------------------------------
__global__ __launch_bounds__(256) void k0_convert(
    const float* __restrict__ x, const float* __restrict__ in_w,
    const float* __restrict__ xp_w, const float* __restrict__ out_w,
    bf16* __restrict__ xb, bf16* __restrict__ wbin,
    bf16* __restrict__ wbxp, bf16* __restrict__ wbout)
{
  const int base = (blockIdx.x * 256 + threadIdx.x) * 4;
  if (base < NX) {
    f32x4 v = *(const f32x4*)(x + base);
    *(short4v*)((short*)xb + base) =
        short4v{f2bs(v[0]), f2bs(v[1]), f2bs(v[2]), f2bs(v[3])};
  } else if (base < NX + NIW) {
    const int off = base - NX;
    f32x4 v = *(const f32x4*)(in_w + off);
    *(short4v*)((short*)wbin + off) =
        short4v{f2bs(v[0]), f2bs(v[1]), f2bs(v[2]), f2bs(v[3])};
  } else if (base < NX + NIW + NXP) {
    const int off = base - NX - NIW;
    short4v s;
    if (off < 33 * HD) {
      f32x4 v = *(const f32x4*)(xp_w + off);
      s = short4v{f2bs(v[0]), f2bs(v[1]), f2bs(v[2]), f2bs(v[3])};
    } else {
      s = short4v{0, 0, 0, 0};
    }
    *(short4v*)((short*)wbxp + off) = s;
  } else if (base < NX + NIW + NXP + NOW) {
    const int off = base - NX - NIW - NXP;
    f32x4 v = *(const f32x4*)(out_w + off);
    *(short4v*)((short*)wbout + off) =
        short4v{f2bs(v[0]), f2bs(v[1]), f2bs(v[2]), f2bs(v[3])};
  }
}

// ---------------------------------------------------------------------------
// K1: tiled GEMM  [x_inner|z] = xb @ in_w^T + in_b  (bf16 out)
// Block tile 128 rows x 128 cols; grid = 128 rt x 4 ct = 512 blocks (2/CU).
// B column-slice LDS-resident; A direct 16B global frags; wave tile 64x64:
// 16 MFMA : 4 global loads per k-step. Epilogue via aliased fp32 LDS tile.
// ---------------------------------------------------------------------------
__global__ __launch_bounds__(256) void k1_gemm(
    const bf16* __restrict__ xb, const bf16* __restrict__ wbin,
    const float* __restrict__ in_b, bf16* __restrict__ xib,
    bf16* __restrict__ zb)
{
  __shared__ __align__(16) char smem[128 * 264 * 2];   // 67,584 B
  bf16* Bt = (bf16*)smem;        // [128][264] bf16 (k-major, +8 pad)
  float* Ct = (float*)smem;      // [128][132] f32 (aliased after GEMM)

  const int tid = threadIdx.x;
  const int rt = blockIdx.x >> 2, ct = blockIdx.x & 3;
  const int R0 = rt * 128, C0 = ct * 128;
  const int wave = tid >> 6, lane = tid & 63, q = lane >> 4, l16 = lane & 15;

  // ---- stage B slice: wbin rows C0..C0+127 (256 k each) ----
#pragma unroll
  for (int it = 0; it < 16; ++it) {
    const int f = tid + it * 256;           // 128 rows x 32 groups of 8
    const int row = f >> 5, g = f & 31;
    bf16x8 v = *(const bf16x8*)(wbin + (size_t)(C0 + row) * HD + g * 8);
    *(bf16x8*)(Bt + row * 264 + g * 8) = v;
  }
  __syncthreads();

  // ---- GEMM: wave = 64x64 quadrant ----
  const int rowHalf = (wave & 1) * 64;
  const int colHalf = (wave >> 1) * 64;
  f32x4 acc[4][4] = {};
  const bf16* ap = xb + (size_t)(R0 + rowHalf + l16) * HD + q * 8;
#pragma unroll
  for (int k = 0; k < HD; k += 32) {
    bf16x8 a[4], b[4];
#pragma unroll
    for (int i = 0; i < 4; ++i)
      a[i] = *(const bf16x8*)(ap + (size_t)i * 16 * HD + k);
#pragma unroll
    for (int j = 0; j < 4; ++j)
      b[j] = *(const bf16x8*)(Bt + (colHalf + j * 16 + l16) * 264 + k + q * 8);
#pragma unroll
    for (int i = 0; i < 4; ++i)
#pragma unroll
      for (int j = 0; j < 4; ++j)
        acc[i][j] = __builtin_amdgcn_mfma_f32_16x16x32_bf16(a[i], b[j], acc[i][j], 0, 0, 0);
  }
  __syncthreads();   // Bt reads complete before Ct overwrite

  // ---- bias + acc -> Ct (C/D: col=l16, row=q*4+r) ----
#pragma unroll
  for (int j = 0; j < 4; ++j) {
    const int col = colHalf + j * 16 + l16;
    const float bias = in_b[C0 + col];
#pragma unroll
    for (int i = 0; i < 4; ++i)
#pragma unroll
      for (int r = 0; r < 4; ++r)
        Ct[(rowHalf + i * 16 + q * 4 + r) * 132 + col] = acc[i][j][r] + bias;
  }
  __syncthreads();

  // ---- coalesced bf16 copy-out ----
  bf16* dst = (C0 < HD) ? xib : zb;
  const int Cd = (C0 < HD) ? C0 : (C0 - HD);
#pragma unroll
  for (int it = 0; it < 8; ++it) {
    const int f = tid + it * 256;           // 128 rows x 16 groups of 8
    const int row = f >> 4, g = f & 15;
    bf16x8 v = cvt_frag(Ct + row * 132 + g * 8);
    *(bf16x8*)(dst + (size_t)(R0 + row) * HD + Cd + g * 8) = v;
  }
}

// ---------------------------------------------------------------------------
// K2: per 32-row chunk: dbc = x_inner @ xp_w^T + xp_b (all-LDS GEMM) +
// chunk-sum Mc[c][s][h]. 256 thr; xt + wbxp staged to LDS.
// ---------------------------------------------------------------------------
__global__ __launch_bounds__(256) void k2_xp_sum(
    const bf16* __restrict__ xib, const bf16* __restrict__ wbxp,
    const float* __restrict__ xp_b, const float* __restrict__ dt_w,
    const float* __restrict__ dt_b, float* __restrict__ dbc,
    float* __restrict__ Mc)
{
  __shared__ bf16 xt[32 * 264];     // 16.9 KB
  __shared__ bf16 wp[48 * 264];     // 25.3 KB
  __shared__ float sdbc[32][33];    // 4.2 KB
  const int tid = threadIdx.x;
  const int R0 = blockIdx.x * CHUNK;
  const int wave = tid >> 6, lane = tid & 63, q = lane >> 4, l16 = lane & 15;

  // stage xt (32x256) and wp (48x256)
#pragma unroll
  for (int it = 0; it < 4; ++it) {
    const int f = tid + it * 256, row = f >> 5, g = f & 31;
    *(bf16x8*)(xt + row * 264 + g * 8) =
        *(const bf16x8*)(xib + (size_t)(R0 + row) * HD + g * 8);
  }
#pragma unroll
  for (int it = 0; it < 6; ++it) {
    const int f = tid + it * 256, row = f >> 5, g = f & 31;
    *(bf16x8*)(wp + row * 264 + g * 8) =
        *(const bf16x8*)(wbxp + (size_t)row * HD + g * 8);
  }
  __syncthreads();

  // xp-GEMM: waves 0,1 handle 16 rows each
  if (wave < 2) {
    f32x4 pacc[3] = {};
#pragma unroll
    for (int k = 0; k < HD; k += 32) {
      bf16x8 af = *(const bf16x8*)(xt + (wave * 16 + l16) * 264 + k + q * 8);
#pragma unroll
      for (int t = 0; t < 3; ++t) {
        bf16x8 bfr = *(const bf16x8*)(wp + (t * 16 + l16) * 264 + k + q * 8);
        pacc[t] = __builtin_amdgcn_mfma_f32_16x16x32_bf16(af, bfr, pacc[t], 0, 0, 0);
      }
    }
#pragma unroll
    for (int t = 0; t < 3; ++t) {
      const int col = t * 16 + l16;
      if (col < 33) {
        const float bias = xp_b[col];
#pragma unroll
        for (int r = 0; r < 4; ++r)
          sdbc[wave * 16 + q * 4 + r][col] = pacc[t][r] + bias;
      }
    }
  }
  __syncthreads();

  // dbc copy (flat) + chunk-sum
  {
    const float* sflat = &sdbc[0][0];
    for (int idx = tid; idx < CHUNK * 33; idx += 256)
      dbc[(size_t)R0 * 33 + idx] = sflat[idx];
  }
  {
    const int h = tid;
    const float dtw = dt_w[h], dtb = dt_b[h];
    float st[SD] = {};
#pragma unroll
    for (int n = 0; n < CHUNK; ++n) {
      const float xv = b2f(xt[n * 264 + h]);
      const float dt = softplus_f(sdbc[n][0] * dtw + dtb);
      const float u = xv * dt;
#pragma unroll
      for (int s = 0; s < SD; ++s) st[s] += u * sdbc[n][1 + s];
    }
    const int b = R0 >> 13, c = (R0 & (NSEQ - 1)) >> 5;
    float* mp = Mc + ((size_t)(b * NCHUNK + c)) * 4096 + h;   // [s][h]
#pragma unroll
    for (int s = 0; s < SD; ++s) mp[s * HD] = st[s];
  }
}

// ---------------------------------------------------------------------------
// K4a: exclusive prefix of Mc within each group of GSZ chunks; totals -> Gs.
// ---------------------------------------------------------------------------
__global__ __launch_bounds__(256) void k4a_prefix_local(
    float* __restrict__ Mc, float* __restrict__ Gs)
{
  const int tid = blockIdx.x * 256 + threadIdx.x;   // 131072
  const int b = tid >> 16;
  const int g = (tid >> 12) & (NGRP - 1);
  const int hs = tid & 4095;
  float run = 0.f;
#pragma unroll
  for (int i = 0; i < GSZ; ++i) {
    const size_t idx = ((size_t)(b * NCHUNK + g * GSZ + i)) * 4096 + hs;
    const float v = Mc[idx];
    Mc[idx] = run;
    run += v;
  }
  Gs[((size_t)(b * NGRP + g)) * 4096 + hs] = run;
}

// ---------------------------------------------------------------------------
// K4b: exclusive prefix over the NGRP group totals (in-place).
// ---------------------------------------------------------------------------
__global__ __launch_bounds__(256) void k4b_prefix_groups(float* __restrict__ Gs)
{
  const int tid = blockIdx.x * 256 + threadIdx.x;   // 8192
  const int b = tid >> 12;
  const int hs = tid & 4095;
  float run = 0.f;
#pragma unroll
  for (int g = 0; g < NGRP; ++g) {
    const size_t idx = ((size_t)(b * NGRP + g)) * 4096 + hs;
    const float v = Gs[idx];
    Gs[idx] = run;
    run += v;
  }
}

// ---------------------------------------------------------------------------
// K56: seeded scan (s-split) -> y -> out GEMM (wave tile 32x32, 2:1
// MFMA:global ratio) + residual + LayerNorm. 512 thr / 8 waves per chunk.
// ---------------------------------------------------------------------------
__global__ __launch_bounds__(512) void k56_scan_out_ln(
    const bf16* __restrict__ xib, const bf16* __restrict__ zb,
    const float* __restrict__ dbc, const float* __restrict__ dt_w,
    const float* __restrict__ dt_b, const float* __restrict__ Dv,
    const float* __restrict__ Mc, const float* __restrict__ Gs,
    const bf16* __restrict__ wbout, const float* __restrict__ out_b,
    const float* __restrict__ x, const float* __restrict__ ln_g,
    const float* __restrict__ ln_b, float* __restrict__ out)
{
  __shared__ float sdbc[CHUNK][33];   // 4.2 KB
  __shared__ float yt[32][260];       // 33.3 KB
  __shared__ float pt[32][260];       // 33.3 KB
  const int tid = threadIdx.x;
  const int wave = tid >> 6, lane = tid & 63, q = lane >> 4, l16 = lane & 15;
  const int R0 = blockIdx.x * CHUNK;
  const int b = R0 >> 13;
  const int cchunk = (R0 & (NSEQ - 1)) >> 5;

  for (int idx = tid; idx < CHUNK * 33; idx += 512) {
    const int n = idx / 33, j = idx - n * 33;
    sdbc[n][j] = dbc[(size_t)(R0 + n) * 33 + j];
  }
  __syncthreads();

  // ---- scan halves: thread = (h, s-half) ----
  {
    const int h = tid & 255;
    const int sh = tid >> 8;
    const float dtw = dt_w[h], dtb = dt_b[h];
    const float dv = Dv[h];
    float st[8];
    const float* mp = Mc + ((size_t)(b * NCHUNK + cchunk)) * 4096 + sh * 8 * HD + h;
    const float* gp = Gs + ((size_t)(b * NGRP + cchunk / GSZ)) * 4096 + sh * 8 * HD + h;
#pragma unroll
    for (int s = 0; s < 8; ++s) st[s] = mp[s * HD] + gp[s * HD];
    float (*dst)[260] = (sh == 0) ? yt : pt;
    for (int n = 0; n < CHUNK; ++n) {
      const float xv = b2f(xib[(size_t)(R0 + n) * HD + h]);
      const float dt = softplus_f(sdbc[n][0] * dtw + dtb);
      const float u = xv * dt;
      float y = (sh == 0) ? dv * xv : 0.f;
#pragma unroll
      for (int s = 0; s < 8; ++s) {
        st[s] += u * sdbc[n][1 + sh * 8 + s];
        y += st[s] * sdbc[n][17 + sh * 8 + s];
      }
      dst[n][h] = y;
    }
  }
  __syncthreads();

  // ---- combine halves + silu(z) gate -> yt ----
  {
    const int h = tid & 255;
    const int r2 = tid >> 8;
#pragma unroll
    for (int j = 0; j < 16; ++j) {
      const int row = r2 * 16 + j;
      const float zv = b2f(zb[(size_t)(R0 + row) * HD + h]);
      const float sig = 1.f / (1.f + __expf(-zv));
      yt[row][h] = (yt[row][h] + pt[row][h]) * zv * sig;
    }
  }
  __syncthreads();

  // ---- out GEMM: wave = 32 rows x 32 cols (cols wave*32..) ----
  const int cw = wave * 32;
  f32x4 acc[2][2] = {};
#pragma unroll
  for (int k = 0; k < HD; k += 32) {
    bf16x8 a0 = cvt_frag(&yt[l16][k + q * 8]);
    bf16x8 a1 = cvt_frag(&yt[16 + l16][k + q * 8]);
#pragma unroll
    for (int t = 0; t < 2; ++t) {
      bf16x8 bfr = *(const bf16x8*)(wbout + (size_t)(cw + t * 16 + l16) * HD + k + q * 8);
      acc[0][t] = __builtin_amdgcn_mfma_f32_16x16x32_bf16(a0, bfr, acc[0][t], 0, 0, 0);
      acc[1][t] = __builtin_amdgcn_mfma_f32_16x16x32_bf16(a1, bfr, acc[1][t], 0, 0, 0);
    }
  }
  __syncthreads();   // yt reads done

  // ---- r = acc + out_b + residual -> pt ----
#pragma unroll
  for (int t = 0; t < 2; ++t) {
    const int col = cw + t * 16 + l16;
    const float bias = out_b[col];
#pragma unroll
    for (int i = 0; i < 2; ++i)
#pragma unroll
      for (int r = 0; r < 4; ++r) {
        const int row = i * 16 + q * 4 + r;
        pt[row][col] = acc[i][t][r] + bias + x[(size_t)(R0 + row) * HD + col];
      }
  }
  __syncthreads();

  // ---- LayerNorm: wave handles rows wave*4 .. wave*4+3 ----
#pragma unroll
  for (int rr = 0; rr < 4; ++rr) {
    const int row = wave * 4 + rr;
    float p = 0.f;
#pragma unroll
    for (int j = 0; j < 4; ++j) p += pt[row][lane + 64 * j];
#pragma unroll
    for (int off = 32; off > 0; off >>= 1) p += __shfl_xor(p, off);
    const float mu = p * (1.f / 256.f);
    float v2 = 0.f;
#pragma unroll
    for (int j = 0; j < 4; ++j) {
      const float d = pt[row][lane + 64 * j] - mu;
      v2 += d * d;
    }
#pragma unroll
    for (int off = 32; off > 0; off >>= 1) v2 += __shfl_xor(v2, off);
    const float rstd = rsqrtf(v2 * (1.f / 256.f) + LN_EPS);
    const size_t base = (size_t)(R0 + row) * HD;
#pragma unroll
    for (int j = 0; j < 4; ++j) {
      const int cc = lane + 64 * j;
      out[base + cc] = ln_g[cc] * (pt[row][cc] - mu) * rstd + ln_b[cc];
    }
  }
}

// ---------------------------------------------------------------------------
extern "C" void kernel_launch(void* const* d_in, const int* in_sizes, int n_in,
                              void* d_out, int out_size, void* d_ws, size_t ws_size,
                              hipStream_t stream)
{
  const float* x     = (const float*)d_in[0];
  const float* in_w  = (const float*)d_in[1];
  const float* in_b  = (const float*)d_in[2];
  const float* xp_w  = (const float*)d_in[3];
  const float* xp_b  = (const float*)d_in[4];
  const float* dt_w  = (const float*)d_in[5];
  const float* dt_b  = (const float*)d_in[6];
  // d_in[7] = A_log — unused by the reference
  const float* Dv    = (const float*)d_in[8];
  const float* out_w = (const float*)d_in[9];
  const float* out_b = (const float*)d_in[10];
  const float* ln_g  = (const float*)d_in[11];
  const float* ln_b  = (const float*)d_in[12];

  char* ws = (char*)d_ws;
  bf16*  xib   = (bf16*)(ws);               // 8,388,608 B
  bf16*  zb    = (bf16*)(ws +  8388608);    // 8,388,608 B
  bf16*  xb    = (bf16*)(ws + 16777216);    // 8,388,608 B
  float* dbc   = (float*)(ws + 25165824);   // 2,162,688 B
  float* Mc    = (float*)(ws + 27328512);   // 8,388,608 B
  float* Gs    = (float*)(ws + 35717120);   //   524,288 B
  bf16*  wbin  = (bf16*)(ws + 36241408);    //   262,144 B
  bf16*  wbxp  = (bf16*)(ws + 36503552);    //    24,576 B
  bf16*  wbout = (bf16*)(ws + 36528128);    //   131,072 B
  float* out   = (float*)d_out;

  hipLaunchKernelGGL(k0_convert, dim3((NX + NIW + NXP + NOW) / 1024), dim3(256),
                     0, stream, x, in_w, xp_w, out_w, xb, wbin, wbxp, wbout);
  hipLaunchKernelGGL(k1_gemm, dim3(512), dim3(256), 0, stream,
                     xb, wbin, in_b, xib, zb);
  hipLaunchKernelGGL(k2_xp_sum, dim3(BN / CHUNK), dim3(256), 0, stream,
                     xib, wbxp, xp_b, dt_w, dt_b, dbc, Mc);
  hipLaunchKernelGGL(k4a_prefix_local, dim3(NBATCH * NGRP * 4096 / 256),
                     dim3(256), 0, stream, Mc, Gs);
  hipLaunchKernelGGL(k4b_prefix_groups, dim3(NBATCH * 4096 / 256), dim3(256),
                     0, stream, Gs);
  hipLaunchKernelGGL(k56_scan_out_ln, dim3(BN / CHUNK), dim3(512), 0, stream,
                     xib, zb, dbc, dt_w, dt_b, Dv, Mc, Gs,
                     wbout, out_b, x, ln_g, ln_b, out);
}

// Round 7
// 143.956 us; speedup vs baseline: 1.1774x; 1.0442x over previous
//
#include <hip/hip_runtime.h>
#include <hip/hip_bf16.h>

// MambaBlock: H=256, S=16, B=2, N=8192. fp32 I/O.
// No decay (A_log unused) => pure prefix-sum SSM, chunk-parallel.
// Round 7: chunked-Mamba matmul form. Per chunk: T = (C@B^T) masked,
// y = T@U + C@Hseed + D*x, Mc = B^T@U -- all via MFMA. Kills the per-step
// LDS broadcast storm that made the scan phases issue-bound.

#define HD 256
#define SD 16
#define NSEQ 8192
#define NBATCH 2
#define BN (NBATCH * NSEQ)      // 16384 rows
#define CHUNK 32
#define NCHUNK (NSEQ / CHUNK)   // 256
#define NGRP 16
#define GSZ (NCHUNK / NGRP)     // 16
#define LN_EPS 1e-5f
#define UST 40                  // bf16 row stride for Ut/Hst/Ct (80 B, 16-aligned)
#define YST 257                 // f32 row stride for yt/pt (conflict-free)

#define NX  (BN * HD)           // 4,194,304 x elements
#define NIW (2 * HD * HD)       // 131,072  in_w
#define NXP (48 * HD)           // 12,288   xp_w padded (src 33*256=8448)
#define NOW (HD * HD)           // 65,536   out_w

typedef __hip_bfloat16 bf16;
typedef __attribute__((ext_vector_type(8))) short bf16x8;
typedef __attribute__((ext_vector_type(4))) short short4v;
typedef __attribute__((ext_vector_type(4))) float f32x4;
typedef __attribute__((ext_vector_type(4))) unsigned int uint4v;
typedef __attribute__((ext_vector_type(2))) unsigned int uint2v;

__device__ __forceinline__ float b2f(bf16 v) { return __bfloat162float(v); }
__device__ __forceinline__ short f2bs(float f) {
  union { bf16 b; short s; } u;
  u.b = __float2bfloat16(f);
  return u.s;
}
__device__ __forceinline__ unsigned int pack2(float a, float b) {
  return (unsigned int)(unsigned short)f2bs(a) |
         ((unsigned int)(unsigned short)f2bs(b) << 16);
}
__device__ __forceinline__ bf16x8 cvt_frag(const float* p) {
  bf16x8 r;
#pragma unroll
  for (int j = 0; j < 8; ++j) r[j] = f2bs(p[j]);
  return r;
}
__device__ __forceinline__ float softplus_f(float a) {
  return (a > 20.f) ? a : __logf(1.f + __expf(a));
}

// ---------------------------------------------------------------------------
// K0: fp32->bf16: x->xb, in_w->wbin, xp_w->wbxp (pad 33->48), out_w->wbout
// ---------------------------------------------------------------------------
__global__ __launch_bounds__(256) void k0_convert(
    const float* __restrict__ x, const float* __restrict__ in_w,
    const float* __restrict__ xp_w, const float* __restrict__ out_w,
    bf16* __restrict__ xb, bf16* __restrict__ wbin,
    bf16* __restrict__ wbxp, bf16* __restrict__ wbout)
{
  const int base = (blockIdx.x * 256 + threadIdx.x) * 4;
  if (base < NX) {
    f32x4 v = *(const f32x4*)(x + base);
    *(short4v*)((short*)xb + base) =
        short4v{f2bs(v[0]), f2bs(v[1]), f2bs(v[2]), f2bs(v[3])};
  } else if (base < NX + NIW) {
    const int off = base - NX;
    f32x4 v = *(const f32x4*)(in_w + off);
    *(short4v*)((short*)wbin + off) =
        short4v{f2bs(v[0]), f2bs(v[1]), f2bs(v[2]), f2bs(v[3])};
  } else if (base < NX + NIW + NXP) {
    const int off = base - NX - NIW;
    short4v s;
    if (off < 33 * HD) {
      f32x4 v = *(const f32x4*)(xp_w + off);
      s = short4v{f2bs(v[0]), f2bs(v[1]), f2bs(v[2]), f2bs(v[3])};
    } else {
      s = short4v{0, 0, 0, 0};
    }
    *(short4v*)((short*)wbxp + off) = s;
  } else if (base < NX + NIW + NXP + NOW) {
    const int off = base - NX - NIW - NXP;
    f32x4 v = *(const f32x4*)(out_w + off);
    *(short4v*)((short*)wbout + off) =
        short4v{f2bs(v[0]), f2bs(v[1]), f2bs(v[2]), f2bs(v[3])};
  }
}

// ---------------------------------------------------------------------------
// K1: tiled GEMM [x_inner|z] = xb @ in_w^T + in_b (bf16 out). Unchanged R6.
// ---------------------------------------------------------------------------
__global__ __launch_bounds__(256) void k1_gemm(
    const bf16* __restrict__ xb, const bf16* __restrict__ wbin,
    const float* __restrict__ in_b, bf16* __restrict__ xib,
    bf16* __restrict__ zb)
{
  __shared__ __align__(16) char smem[128 * 264 * 2];
  bf16* Bt = (bf16*)smem;
  float* Ct = (float*)smem;

  const int tid = threadIdx.x;
  const int rt = blockIdx.x >> 2, ct = blockIdx.x & 3;
  const int R0 = rt * 128, C0 = ct * 128;
  const int wave = tid >> 6, lane = tid & 63, q = lane >> 4, l16 = lane & 15;

#pragma unroll
  for (int it = 0; it < 16; ++it) {
    const int f = tid + it * 256;
    const int row = f >> 5, g = f & 31;
    bf16x8 v = *(const bf16x8*)(wbin + (size_t)(C0 + row) * HD + g * 8);
    *(bf16x8*)(Bt + row * 264 + g * 8) = v;
  }
  __syncthreads();

  const int rowHalf = (wave & 1) * 64;
  const int colHalf = (wave >> 1) * 64;
  f32x4 acc[4][4] = {};
  const bf16* ap = xb + (size_t)(R0 + rowHalf + l16) * HD + q * 8;
#pragma unroll
  for (int k = 0; k < HD; k += 32) {
    bf16x8 a[4], b[4];
#pragma unroll
    for (int i = 0; i < 4; ++i)
      a[i] = *(const bf16x8*)(ap + (size_t)i * 16 * HD + k);
#pragma unroll
    for (int j = 0; j < 4; ++j)
      b[j] = *(const bf16x8*)(Bt + (colHalf + j * 16 + l16) * 264 + k + q * 8);
#pragma unroll
    for (int i = 0; i < 4; ++i)
#pragma unroll
      for (int j = 0; j < 4; ++j)
        acc[i][j] = __builtin_amdgcn_mfma_f32_16x16x32_bf16(a[i], b[j], acc[i][j], 0, 0, 0);
  }
  __syncthreads();

#pragma unroll
  for (int j = 0; j < 4; ++j) {
    const int col = colHalf + j * 16 + l16;
    const float bias = in_b[C0 + col];
#pragma unroll
    for (int i = 0; i < 4; ++i)
#pragma unroll
      for (int r = 0; r < 4; ++r)
        Ct[(rowHalf + i * 16 + q * 4 + r) * 132 + col] = acc[i][j][r] + bias;
  }
  __syncthreads();

  bf16* dst = (C0 < HD) ? xib : zb;
  const int Cd = (C0 < HD) ? C0 : (C0 - HD);
#pragma unroll
  for (int it = 0; it < 8; ++it) {
    const int f = tid + it * 256;
    const int row = f >> 4, g = f & 15;
    bf16x8 v = cvt_frag(Ct + row * 132 + g * 8);
    *(bf16x8*)(dst + (size_t)(R0 + row) * HD + Cd + g * 8) = v;
  }
}

// ---------------------------------------------------------------------------
// KS: per 32-row chunk: xp-GEMM -> dbc + (sdt,B,C); u = x*softplus(dt);
// Ut[h][n] bf16; Mc = B^T @ U via MFMA; T = (C@B^T) lower-tri mask -> Tg.
// ---------------------------------------------------------------------------
__global__ __launch_bounds__(256) void kS_xp_sum(
    const bf16* __restrict__ xib, const bf16* __restrict__ wbxp,
    const float* __restrict__ xp_b, const float* __restrict__ dt_w,
    const float* __restrict__ dt_b, float* __restrict__ dbc,
    bf16* __restrict__ Tg, float* __restrict__ Mc)
{
  __shared__ __align__(16) bf16 xt[32 * 264];    // 16.9 KB
  __shared__ __align__(16) bf16 wp[48 * 264];    // 25.3 KB
  __shared__ __align__(16) float sdbc[32][33];   // 4.2 KB
  __shared__ __align__(16) bf16 sBt[16 * UST];   // 1.25 KB  [s][n]
  __shared__ __align__(16) bf16 Ut[256 * UST];   // 20 KB    [h][n]
  const int tid = threadIdx.x;
  const int wave = tid >> 6, lane = tid & 63, q = lane >> 4, l16 = lane & 15;
  const int cix = blockIdx.x;
  const int R0 = cix * CHUNK;

  // stage xt (32x256) and wp (48x256)
#pragma unroll
  for (int it = 0; it < 4; ++it) {
    const int f = tid + it * 256, row = f >> 5, g = f & 31;
    *(bf16x8*)(xt + row * 264 + g * 8) =
        *(const bf16x8*)(xib + (size_t)(R0 + row) * HD + g * 8);
  }
#pragma unroll
  for (int it = 0; it < 6; ++it) {
    const int f = tid + it * 256, row = f >> 5, g = f & 31;
    *(bf16x8*)(wp + row * 264 + g * 8) =
        *(const bf16x8*)(wbxp + (size_t)row * HD + g * 8);
  }
  __syncthreads();

  // xp-GEMM: waves 0,1 -> 16 rows each
  if (wave < 2) {
    f32x4 pacc[3] = {};
#pragma unroll
    for (int k = 0; k < HD; k += 32) {
      bf16x8 af = *(const bf16x8*)(xt + (wave * 16 + l16) * 264 + k + q * 8);
#pragma unroll
      for (int t = 0; t < 3; ++t) {
        bf16x8 bfr = *(const bf16x8*)(wp + (t * 16 + l16) * 264 + k + q * 8);
        pacc[t] = __builtin_amdgcn_mfma_f32_16x16x32_bf16(af, bfr, pacc[t], 0, 0, 0);
      }
    }
#pragma unroll
    for (int t = 0; t < 3; ++t) {
      const int col = t * 16 + l16;
      if (col < 33) {
        const float bias = xp_b[col];
#pragma unroll
        for (int r = 0; r < 4; ++r) {
          const int row = wave * 16 + q * 4 + r;
          const float v = pacc[t][r] + bias;
          sdbc[row][col] = v;
          if (col >= 1 && col < 17)
            *((short*)sBt + (col - 1) * UST + row) = f2bs(v);
        }
      }
    }
  }
  __syncthreads();

  // dbc flat copy out
  {
    const float* sflat = &sdbc[0][0];
    for (int idx = tid; idx < CHUNK * 33; idx += 256)
      dbc[(size_t)R0 * 33 + idx] = sflat[idx];
  }
  // u -> Ut[h][n]
  {
    const int h = tid;
    const float dtw = dt_w[h], dtb = dt_b[h];
    unsigned int up[16];
#pragma unroll
    for (int n2 = 0; n2 < 16; ++n2) {
      const int n = 2 * n2;
      const float xv0 = b2f(xt[n * 264 + h]);
      const float xv1 = b2f(xt[(n + 1) * 264 + h]);
      const float u0 = xv0 * softplus_f(sdbc[n][0] * dtw + dtb);
      const float u1 = xv1 * softplus_f(sdbc[n + 1][0] * dtw + dtb);
      up[n2] = pack2(u0, u1);
    }
    uint4v* dst = (uint4v*)(Ut + h * UST);
#pragma unroll
    for (int j = 0; j < 4; ++j)
      dst[j] = uint4v{up[4 * j], up[4 * j + 1], up[4 * j + 2], up[4 * j + 3]};
  }
  // T = (C @ B^T) masked (m <= n), bf16 -> Tg
  {
    const int n = tid >> 3;
    const int m0 = (tid & 7) * 4;
    float cn[SD];
#pragma unroll
    for (int s = 0; s < SD; ++s) cn[s] = sdbc[n][17 + s];
    short4v tv;
#pragma unroll
    for (int mm = 0; mm < 4; ++mm) {
      const int m = m0 + mm;
      float t = 0.f;
#pragma unroll
      for (int s = 0; s < SD; ++s) t += cn[s] * sdbc[m][1 + s];
      tv[mm] = (m <= n) ? f2bs(t) : (short)0;
    }
    *(short4v*)((short*)Tg + (size_t)cix * 1024 + n * 32 + m0) = tv;
  }
  __syncthreads();

  // Mc = B^T @ U : M=16(s) K=32(n) N=256(h); wave w -> col-tiles w*4..w*4+3
  {
    bf16x8 af = *(const bf16x8*)(sBt + l16 * UST + q * 8);
    f32x4 macc[4] = {};
#pragma unroll
    for (int c4 = 0; c4 < 4; ++c4) {
      const int ct = wave * 4 + c4;
      bf16x8 bu = *(const bf16x8*)(Ut + (ct * 16 + l16) * UST + q * 8);
      macc[c4] = __builtin_amdgcn_mfma_f32_16x16x32_bf16(af, bu, macc[c4], 0, 0, 0);
    }
    float* mbase = Mc + (size_t)cix * 4096;
#pragma unroll
    for (int c4 = 0; c4 < 4; ++c4) {
      const int h = (wave * 4 + c4) * 16 + l16;
#pragma unroll
      for (int r = 0; r < 4; ++r)
        mbase[(q * 4 + r) * HD + h] = macc[c4][r];   // [s][h]
    }
  }
}

// ---------------------------------------------------------------------------
// K4a: exclusive prefix of Mc within each group of GSZ chunks; totals -> Gs.
// ---------------------------------------------------------------------------
__global__ __launch_bounds__(256) void k4a_prefix_local(
    float* __restrict__ Mc, float* __restrict__ Gs)
{
  const int tid = blockIdx.x * 256 + threadIdx.x;   // 131072
  const int b = tid >> 16;
  const int g = (tid >> 12) & (NGRP - 1);
  const int hs = tid & 4095;
  float run = 0.f;
#pragma unroll
  for (int i = 0; i < GSZ; ++i) {
    const size_t idx = ((size_t)(b * NCHUNK + g * GSZ + i)) * 4096 + hs;
    const float v = Mc[idx];
    Mc[idx] = run;
    run += v;
  }
  Gs[((size_t)(b * NGRP + g)) * 4096 + hs] = run;
}

// ---------------------------------------------------------------------------
// K4b: exclusive prefix over the NGRP group totals (in-place).
// ---------------------------------------------------------------------------
__global__ __launch_bounds__(256) void k4b_prefix_groups(float* __restrict__ Gs)
{
  const int tid = blockIdx.x * 256 + threadIdx.x;   // 8192
  const int b = tid >> 12;
  const int hs = tid & 4095;
  float run = 0.f;
#pragma unroll
  for (int g = 0; g < NGRP; ++g) {
    const size_t idx = ((size_t)(b * NGRP + g)) * 4096 + hs;
    const float v = Gs[idx];
    Gs[idx] = run;
    run += v;
  }
}

// ---------------------------------------------------------------------------
// K56: y = T@U + C@Hseed (MFMA) ; gate: y = (y + D*x_in)*silu(z) ;
// out-GEMM + residual + LN. 256 thr / 4 waves. LDS operand tiles aliased
// under the yt/pt region (66 KB -> 2 blocks/CU).
// ---------------------------------------------------------------------------
__global__ __launch_bounds__(256) void k56_scan_out_ln(
    const bf16* __restrict__ xib, const bf16* __restrict__ zb,
    const float* __restrict__ dbc, const bf16* __restrict__ Tg,
    const float* __restrict__ dt_w, const float* __restrict__ dt_b,
    const float* __restrict__ Dv, const float* __restrict__ Mc,
    const float* __restrict__ Gs, const bf16* __restrict__ wbout,
    const float* __restrict__ out_b, const float* __restrict__ x,
    const float* __restrict__ ln_g, const float* __restrict__ ln_b,
    float* __restrict__ out)
{
  __shared__ __align__(16) char un[2 * 32 * YST * 4];   // 65,792 B union
  bf16* Ut  = (bf16*)un;                 // [256][UST]  20,480 B
  bf16* Hst = (bf16*)(un + 20480);       // [256][UST]  20,480 B
  bf16* Ctl = (bf16*)(un + 40960);       // [32][UST]    2,560 B
  bf16* Tt  = (bf16*)(un + 43520);       // [32][32]     2,048 B
  float* yt = (float*)un;                // phase2: [32][YST]
  float* pt = (float*)(un + 32 * YST * 4);
  __shared__ float sdt[32];

  const int tid = threadIdx.x;
  const int wave = tid >> 6, lane = tid & 63, q = lane >> 4, l16 = lane & 15;
  const int cix = blockIdx.x;
  const int R0 = cix * CHUNK;
  const int b = cix >> 8;
  const int cchunk = cix & 255;

  // ---- build operand tiles ----
  // Tt copy (1024 bf16)
  *(short4v*)((short*)Tt + tid * 4) =
      *(const short4v*)((const short*)Tg + (size_t)cix * 1024 + tid * 4);
  // sdt
  if (tid < 32) sdt[tid] = dbc[(size_t)(R0 + tid) * 33];
  // Ctl[n][k] = C (k<16) else 0
  {
    const int n = tid >> 3, k0 = (tid & 7) * 4;
    float v[4];
#pragma unroll
    for (int j = 0; j < 4; ++j) {
      const int k = k0 + j;
      v[j] = (k < SD) ? dbc[(size_t)(R0 + n) * 33 + 17 + k] : 0.f;
    }
    *(uint2v*)((short*)Ctl + n * UST + k0) = uint2v{pack2(v[0], v[1]), pack2(v[2], v[3])};
  }
  // Hst[h][s] = seed (k<16) else 0
  {
    const int h = tid;
    const float* mp = Mc + (size_t)cix * 4096 + h;
    const float* gp = Gs + ((size_t)(b * NGRP + cchunk / GSZ)) * 4096 + h;
    unsigned int hp[8];
#pragma unroll
    for (int s2 = 0; s2 < 8; ++s2) {
      const int s = 2 * s2;
      const float v0 = mp[s * HD] + gp[s * HD];
      const float v1 = mp[(s + 1) * HD] + gp[(s + 1) * HD];
      hp[s2] = pack2(v0, v1);
    }
    uint4v* hd = (uint4v*)(Hst + h * UST);
    hd[0] = uint4v{hp[0], hp[1], hp[2], hp[3]};
    hd[1] = uint4v{hp[4], hp[5], hp[6], hp[7]};
    hd[2] = uint4v{0, 0, 0, 0};
    hd[3] = uint4v{0, 0, 0, 0};
  }
  __syncthreads();   // sdt ready before u-compute

  // u -> Ut[h][n]
  {
    const int h = tid;
    const float dtw = dt_w[h], dtb = dt_b[h];
    unsigned int up[16];
#pragma unroll
    for (int n2 = 0; n2 < 16; ++n2) {
      const int n = 2 * n2;
      const float xv0 = b2f(xib[(size_t)(R0 + n) * HD + h]);
      const float xv1 = b2f(xib[(size_t)(R0 + n + 1) * HD + h]);
      const float u0 = xv0 * softplus_f(sdt[n] * dtw + dtb);
      const float u1 = xv1 * softplus_f(sdt[n + 1] * dtw + dtb);
      up[n2] = pack2(u0, u1);
    }
    uint4v* dst = (uint4v*)(Ut + h * UST);
#pragma unroll
    for (int j = 0; j < 4; ++j)
      dst[j] = uint4v{up[4 * j], up[4 * j + 1], up[4 * j + 2], up[4 * j + 3]};
  }
  __syncthreads();

  // ---- y MFMAs: wave -> col-tiles wave*4..wave*4+3, 2 row-tiles ----
  f32x4 acc[2][4] = {};
  {
    bf16x8 aT0 = *(const bf16x8*)(Tt + l16 * 32 + q * 8);
    bf16x8 aT1 = *(const bf16x8*)(Tt + (16 + l16) * 32 + q * 8);
    bf16x8 aC0 = *(const bf16x8*)(Ctl + l16 * UST + q * 8);
    bf16x8 aC1 = *(const bf16x8*)(Ctl + (16 + l16) * UST + q * 8);
#pragma unroll
    for (int c4 = 0; c4 < 4; ++c4) {
      const int ct = wave * 4 + c4;
      bf16x8 bu = *(const bf16x8*)(Ut + (ct * 16 + l16) * UST + q * 8);
      bf16x8 bh = *(const bf16x8*)(Hst + (ct * 16 + l16) * UST + q * 8);
      acc[0][c4] = __builtin_amdgcn_mfma_f32_16x16x32_bf16(aT0, bu, acc[0][c4], 0, 0, 0);
      acc[0][c4] = __builtin_amdgcn_mfma_f32_16x16x32_bf16(aC0, bh, acc[0][c4], 0, 0, 0);
      acc[1][c4] = __builtin_amdgcn_mfma_f32_16x16x32_bf16(aT1, bu, acc[1][c4], 0, 0, 0);
      acc[1][c4] = __builtin_amdgcn_mfma_f32_16x16x32_bf16(aC1, bh, acc[1][c4], 0, 0, 0);
    }
  }
  __syncthreads();   // operand tiles dead; union becomes yt/pt

  // acc -> yt
#pragma unroll
  for (int c4 = 0; c4 < 4; ++c4) {
    const int h = (wave * 4 + c4) * 16 + l16;
#pragma unroll
    for (int rt = 0; rt < 2; ++rt)
#pragma unroll
      for (int r = 0; r < 4; ++r)
        yt[(rt * 16 + q * 4 + r) * YST + h] = acc[rt][c4][r];
  }
  __syncthreads();

  // gate: y = (y + D*x_inner) * silu(z)
  {
    const int h = tid;
    const float dh = Dv[h];
#pragma unroll
    for (int n = 0; n < CHUNK; ++n) {
      const size_t row = (size_t)(R0 + n) * HD + h;
      const float yv = yt[n * YST + h] + dh * b2f(xib[row]);
      const float zv = b2f(zb[row]);
      const float sig = 1.f / (1.f + __expf(-zv));
      yt[n * YST + h] = yv * zv * sig;
    }
  }
  __syncthreads();

  // ---- out GEMM: wave = 32 rows x 64 cols ----
  const int cw = wave * 64;
  f32x4 oacc[2][4] = {};
#pragma unroll
  for (int k = 0; k < HD; k += 32) {
    bf16x8 a0 = cvt_frag(&yt[l16 * YST + k + q * 8]);
    bf16x8 a1 = cvt_frag(&yt[(16 + l16) * YST + k + q * 8]);
#pragma unroll
    for (int t = 0; t < 4; ++t) {
      bf16x8 bfr = *(const bf16x8*)(wbout + (size_t)(cw + t * 16 + l16) * HD + k + q * 8);
      oacc[0][t] = __builtin_amdgcn_mfma_f32_16x16x32_bf16(a0, bfr, oacc[0][t], 0, 0, 0);
      oacc[1][t] = __builtin_amdgcn_mfma_f32_16x16x32_bf16(a1, bfr, oacc[1][t], 0, 0, 0);
    }
  }
  // pt = oacc + out_b + residual (pt region disjoint from yt)
#pragma unroll
  for (int t = 0; t < 4; ++t) {
    const int col = cw + t * 16 + l16;
    const float bias = out_b[col];
#pragma unroll
    for (int rt = 0; rt < 2; ++rt)
#pragma unroll
      for (int r = 0; r < 4; ++r) {
        const int row = rt * 16 + q * 4 + r;
        pt[row * YST + col] = oacc[rt][t][r] + bias + x[(size_t)(R0 + row) * HD + col];
      }
  }
  __syncthreads();

  // ---- LayerNorm: wave handles rows wave*8 .. wave*8+7 ----
#pragma unroll
  for (int rr = 0; rr < 8; ++rr) {
    const int row = wave * 8 + rr;
    float p = 0.f;
#pragma unroll
    for (int j = 0; j < 4; ++j) p += pt[row * YST + lane + 64 * j];
#pragma unroll
    for (int off = 32; off > 0; off >>= 1) p += __shfl_xor(p, off);
    const float mu = p * (1.f / 256.f);
    float v2 = 0.f;
#pragma unroll
    for (int j = 0; j < 4; ++j) {
      const float d = pt[row * YST + lane + 64 * j] - mu;
      v2 += d * d;
    }
#pragma unroll
    for (int off = 32; off > 0; off >>= 1) v2 += __shfl_xor(v2, off);
    const float rstd = rsqrtf(v2 * (1.f / 256.f) + LN_EPS);
    const size_t base = (size_t)(R0 + row) * HD;
#pragma unroll
    for (int j = 0; j < 4; ++j) {
      const int cc = lane + 64 * j;
      out[base + cc] = ln_g[cc] * (pt[row * YST + cc] - mu) * rstd + ln_b[cc];
    }
  }
}

// ---------------------------------------------------------------------------
extern "C" void kernel_launch(void* const* d_in, const int* in_sizes, int n_in,
                              void* d_out, int out_size, void* d_ws, size_t ws_size,
                              hipStream_t stream)
{
  const float* x     = (const float*)d_in[0];
  const float* in_w  = (const float*)d_in[1];
  const float* in_b  = (const float*)d_in[2];
  const float* xp_w  = (const float*)d_in[3];
  const float* xp_b  = (const float*)d_in[4];
  const float* dt_w  = (const float*)d_in[5];
  const float* dt_b  = (const float*)d_in[6];
  // d_in[7] = A_log — unused by the reference
  const float* Dv    = (const float*)d_in[8];
  const float* out_w = (const float*)d_in[9];
  const float* out_b = (const float*)d_in[10];
  const float* ln_g  = (const float*)d_in[11];
  const float* ln_b  = (const float*)d_in[12];

  char* ws = (char*)d_ws;
  bf16*  xib   = (bf16*)(ws);               // 8,388,608 B
  bf16*  zb    = (bf16*)(ws +  8388608);    // 8,388,608 B
  bf16*  xb    = (bf16*)(ws + 16777216);    // 8,388,608 B
  float* dbc   = (float*)(ws + 25165824);   // 2,162,688 B
  float* Mc    = (float*)(ws + 27328512);   // 8,388,608 B
  float* Gs    = (float*)(ws + 35717120);   //   524,288 B
  bf16*  wbin  = (bf16*)(ws + 36241408);    //   262,144 B
  bf16*  wbxp  = (bf16*)(ws + 36503552);    //    24,576 B
  bf16*  wbout = (bf16*)(ws + 36528128);    //   131,072 B
  bf16*  Tg    = (bf16*)(ws + 36659200);    // 1,048,576 B
  float* out   = (float*)d_out;

  hipLaunchKernelGGL(k0_convert, dim3((NX + NIW + NXP + NOW) / 1024), dim3(256),
                     0, stream, x, in_w, xp_w, out_w, xb, wbin, wbxp, wbout);
  hipLaunchKernelGGL(k1_gemm, dim3(512), dim3(256), 0, stream,
                     xb, wbin, in_b, xib, zb);
  hipLaunchKernelGGL(kS_xp_sum, dim3(BN / CHUNK), dim3(256), 0, stream,
                     xib, wbxp, xp_b, dt_w, dt_b, dbc, Tg, Mc);
  hipLaunchKernelGGL(k4a_prefix_local, dim3(NBATCH * NGRP * 4096 / 256),
                     dim3(256), 0, stream, Mc, Gs);
  hipLaunchKernelGGL(k4b_prefix_groups, dim3(NBATCH * 4096 / 256), dim3(256),
                     0, stream, Gs);
  hipLaunchKernelGGL(k56_scan_out_ln, dim3(BN / CHUNK), dim3(256), 0, stream,
                     xib, zb, dbc, Tg, dt_w, dt_b, Dv, Mc, Gs,
                     wbout, out_b, x, ln_g, ln_b, out);
}

// Round 8
// 143.180 us; speedup vs baseline: 1.1838x; 1.0054x over previous
//
#include <hip/hip_runtime.h>
#include <hip/hip_bf16.h>

// MambaBlock: H=256, S=16, B=2, N=8192. fp32 I/O.
// No decay (A_log unused) => pure prefix-sum SSM, chunk-parallel.
// Round 8: k56 rewrite -- T recomputed in-block, gate applied in registers
// on MFMA accumulators, bf16 yb tile for ds_read_b128 out-GEMM fragments.
// kS drops the Tg round-trip.

#define HD 256
#define SD 16
#define NSEQ 8192
#define NBATCH 2
#define BN (NBATCH * NSEQ)      // 16384 rows
#define CHUNK 32
#define NCHUNK (NSEQ / CHUNK)   // 256
#define NGRP 16
#define GSZ (NCHUNK / NGRP)     // 16
#define LN_EPS 1e-5f
#define UST 40                  // bf16 row stride for Ut/Hst/Ctl
#define PST 257                 // f32 row stride for pt

#define NX  (BN * HD)           // 4,194,304 x elements
#define NIW (2 * HD * HD)       // 131,072  in_w
#define NXP (48 * HD)           // 12,288   xp_w padded (src 33*256=8448)
#define NOW (HD * HD)           // 65,536   out_w

typedef __hip_bfloat16 bf16;
typedef __attribute__((ext_vector_type(8))) short bf16x8;
typedef __attribute__((ext_vector_type(4))) short short4v;
typedef __attribute__((ext_vector_type(4))) float f32x4;
typedef __attribute__((ext_vector_type(4))) unsigned int uint4v;
typedef __attribute__((ext_vector_type(2))) unsigned int uint2v;

__device__ __forceinline__ float b2f(bf16 v) { return __bfloat162float(v); }
__device__ __forceinline__ short f2bs(float f) {
  union { bf16 b; short s; } u;
  u.b = __float2bfloat16(f);
  return u.s;
}
__device__ __forceinline__ unsigned int pack2(float a, float b) {
  return (unsigned int)(unsigned short)f2bs(a) |
         ((unsigned int)(unsigned short)f2bs(b) << 16);
}
__device__ __forceinline__ bf16x8 cvt_frag(const float* p) {
  bf16x8 r;
#pragma unroll
  for (int j = 0; j < 8; ++j) r[j] = f2bs(p[j]);
  return r;
}
__device__ __forceinline__ float softplus_f(float a) {
  return (a > 20.f) ? a : __logf(1.f + __expf(a));
}

// ---------------------------------------------------------------------------
// K0: fp32->bf16: x->xb, in_w->wbin, xp_w->wbxp (pad 33->48), out_w->wbout
// ---------------------------------------------------------------------------
__global__ __launch_bounds__(256) void k0_convert(
    const float* __restrict__ x, const float* __restrict__ in_w,
    const float* __restrict__ xp_w, const float* __restrict__ out_w,
    bf16* __restrict__ xb, bf16* __restrict__ wbin,
    bf16* __restrict__ wbxp, bf16* __restrict__ wbout)
{
  const int base = (blockIdx.x * 256 + threadIdx.x) * 4;
  if (base < NX) {
    f32x4 v = *(const f32x4*)(x + base);
    *(short4v*)((short*)xb + base) =
        short4v{f2bs(v[0]), f2bs(v[1]), f2bs(v[2]), f2bs(v[3])};
  } else if (base < NX + NIW) {
    const int off = base - NX;
    f32x4 v = *(const f32x4*)(in_w + off);
    *(short4v*)((short*)wbin + off) =
        short4v{f2bs(v[0]), f2bs(v[1]), f2bs(v[2]), f2bs(v[3])};
  } else if (base < NX + NIW + NXP) {
    const int off = base - NX - NIW;
    short4v s;
    if (off < 33 * HD) {
      f32x4 v = *(const f32x4*)(xp_w + off);
      s = short4v{f2bs(v[0]), f2bs(v[1]), f2bs(v[2]), f2bs(v[3])};
    } else {
      s = short4v{0, 0, 0, 0};
    }
    *(short4v*)((short*)wbxp + off) = s;
  } else if (base < NX + NIW + NXP + NOW) {
    const int off = base - NX - NIW - NXP;
    f32x4 v = *(const f32x4*)(out_w + off);
    *(short4v*)((short*)wbout + off) =
        short4v{f2bs(v[0]), f2bs(v[1]), f2bs(v[2]), f2bs(v[3])};
  }
}

// ---------------------------------------------------------------------------
// K1: tiled GEMM [x_inner|z] = xb @ in_w^T + in_b (bf16 out). Unchanged.
// ---------------------------------------------------------------------------
__global__ __launch_bounds__(256) void k1_gemm(
    const bf16* __restrict__ xb, const bf16* __restrict__ wbin,
    const float* __restrict__ in_b, bf16* __restrict__ xib,
    bf16* __restrict__ zb)
{
  __shared__ __align__(16) char smem[128 * 264 * 2];
  bf16* Bt = (bf16*)smem;
  float* Ct = (float*)smem;

  const int tid = threadIdx.x;
  const int rt = blockIdx.x >> 2, ct = blockIdx.x & 3;
  const int R0 = rt * 128, C0 = ct * 128;
  const int wave = tid >> 6, lane = tid & 63, q = lane >> 4, l16 = lane & 15;

#pragma unroll
  for (int it = 0; it < 16; ++it) {
    const int f = tid + it * 256;
    const int row = f >> 5, g = f & 31;
    bf16x8 v = *(const bf16x8*)(wbin + (size_t)(C0 + row) * HD + g * 8);
    *(bf16x8*)(Bt + row * 264 + g * 8) = v;
  }
  __syncthreads();

  const int rowHalf = (wave & 1) * 64;
  const int colHalf = (wave >> 1) * 64;
  f32x4 acc[4][4] = {};
  const bf16* ap = xb + (size_t)(R0 + rowHalf + l16) * HD + q * 8;
#pragma unroll
  for (int k = 0; k < HD; k += 32) {
    bf16x8 a[4], b[4];
#pragma unroll
    for (int i = 0; i < 4; ++i)
      a[i] = *(const bf16x8*)(ap + (size_t)i * 16 * HD + k);
#pragma unroll
    for (int j = 0; j < 4; ++j)
      b[j] = *(const bf16x8*)(Bt + (colHalf + j * 16 + l16) * 264 + k + q * 8);
#pragma unroll
    for (int i = 0; i < 4; ++i)
#pragma unroll
      for (int j = 0; j < 4; ++j)
        acc[i][j] = __builtin_amdgcn_mfma_f32_16x16x32_bf16(a[i], b[j], acc[i][j], 0, 0, 0);
  }
  __syncthreads();

#pragma unroll
  for (int j = 0; j < 4; ++j) {
    const int col = colHalf + j * 16 + l16;
    const float bias = in_b[C0 + col];
#pragma unroll
    for (int i = 0; i < 4; ++i)
#pragma unroll
      for (int r = 0; r < 4; ++r)
        Ct[(rowHalf + i * 16 + q * 4 + r) * 132 + col] = acc[i][j][r] + bias;
  }
  __syncthreads();

  bf16* dst = (C0 < HD) ? xib : zb;
  const int Cd = (C0 < HD) ? C0 : (C0 - HD);
#pragma unroll
  for (int it = 0; it < 8; ++it) {
    const int f = tid + it * 256;
    const int row = f >> 4, g = f & 15;
    bf16x8 v = cvt_frag(Ct + row * 132 + g * 8);
    *(bf16x8*)(dst + (size_t)(R0 + row) * HD + Cd + g * 8) = v;
  }
}

// ---------------------------------------------------------------------------
// KS: per 32-row chunk: xp-GEMM -> dbc; u = x*softplus(dt) -> Ut[h][n];
// Mc = B^T @ U via MFMA ([s][h] layout).
// ---------------------------------------------------------------------------
__global__ __launch_bounds__(256) void kS_xp_sum(
    const bf16* __restrict__ xib, const bf16* __restrict__ wbxp,
    const float* __restrict__ xp_b, const float* __restrict__ dt_w,
    const float* __restrict__ dt_b, float* __restrict__ dbc,
    float* __restrict__ Mc)
{
  __shared__ __align__(16) bf16 xt[32 * 264];    // 16.9 KB
  __shared__ __align__(16) bf16 wp[48 * 264];    // 25.3 KB
  __shared__ __align__(16) float sdbc[32][33];   // 4.2 KB
  __shared__ __align__(16) bf16 sBt[16 * UST];   // 1.25 KB  [s][n]
  __shared__ __align__(16) bf16 Ut[256 * UST];   // 20 KB    [h][n]
  const int tid = threadIdx.x;
  const int wave = tid >> 6, lane = tid & 63, q = lane >> 4, l16 = lane & 15;
  const int cix = blockIdx.x;
  const int R0 = cix * CHUNK;

#pragma unroll
  for (int it = 0; it < 4; ++it) {
    const int f = tid + it * 256, row = f >> 5, g = f & 31;
    *(bf16x8*)(xt + row * 264 + g * 8) =
        *(const bf16x8*)(xib + (size_t)(R0 + row) * HD + g * 8);
  }
#pragma unroll
  for (int it = 0; it < 6; ++it) {
    const int f = tid + it * 256, row = f >> 5, g = f & 31;
    *(bf16x8*)(wp + row * 264 + g * 8) =
        *(const bf16x8*)(wbxp + (size_t)row * HD + g * 8);
  }
  __syncthreads();

  if (wave < 2) {
    f32x4 pacc[3] = {};
#pragma unroll
    for (int k = 0; k < HD; k += 32) {
      bf16x8 af = *(const bf16x8*)(xt + (wave * 16 + l16) * 264 + k + q * 8);
#pragma unroll
      for (int t = 0; t < 3; ++t) {
        bf16x8 bfr = *(const bf16x8*)(wp + (t * 16 + l16) * 264 + k + q * 8);
        pacc[t] = __builtin_amdgcn_mfma_f32_16x16x32_bf16(af, bfr, pacc[t], 0, 0, 0);
      }
    }
#pragma unroll
    for (int t = 0; t < 3; ++t) {
      const int col = t * 16 + l16;
      if (col < 33) {
        const float bias = xp_b[col];
#pragma unroll
        for (int r = 0; r < 4; ++r) {
          const int row = wave * 16 + q * 4 + r;
          const float v = pacc[t][r] + bias;
          sdbc[row][col] = v;
          if (col >= 1 && col < 17)
            *((short*)sBt + (col - 1) * UST + row) = f2bs(v);
        }
      }
    }
  }
  __syncthreads();

  // dbc flat copy out
  {
    const float* sflat = &sdbc[0][0];
    for (int idx = tid; idx < CHUNK * 33; idx += 256)
      dbc[(size_t)R0 * 33 + idx] = sflat[idx];
  }
  // u -> Ut[h][n]
  {
    const int h = tid;
    const float dtw = dt_w[h], dtb = dt_b[h];
    unsigned int up[16];
#pragma unroll
    for (int n2 = 0; n2 < 16; ++n2) {
      const int n = 2 * n2;
      const float xv0 = b2f(xt[n * 264 + h]);
      const float xv1 = b2f(xt[(n + 1) * 264 + h]);
      const float u0 = xv0 * softplus_f(sdbc[n][0] * dtw + dtb);
      const float u1 = xv1 * softplus_f(sdbc[n + 1][0] * dtw + dtb);
      up[n2] = pack2(u0, u1);
    }
    uint4v* dst = (uint4v*)(Ut + h * UST);
#pragma unroll
    for (int j = 0; j < 4; ++j)
      dst[j] = uint4v{up[4 * j], up[4 * j + 1], up[4 * j + 2], up[4 * j + 3]};
  }
  __syncthreads();

  // Mc = B^T @ U : wave w -> col-tiles w*4..w*4+3
  {
    bf16x8 af = *(const bf16x8*)(sBt + l16 * UST + q * 8);
    f32x4 macc[4] = {};
#pragma unroll
    for (int c4 = 0; c4 < 4; ++c4) {
      const int ct = wave * 4 + c4;
      bf16x8 bu = *(const bf16x8*)(Ut + (ct * 16 + l16) * UST + q * 8);
      macc[c4] = __builtin_amdgcn_mfma_f32_16x16x32_bf16(af, bu, macc[c4], 0, 0, 0);
    }
    float* mbase = Mc + (size_t)cix * 4096;
#pragma unroll
    for (int c4 = 0; c4 < 4; ++c4) {
      const int h = (wave * 4 + c4) * 16 + l16;
#pragma unroll
      for (int r = 0; r < 4; ++r)
        mbase[(q * 4 + r) * HD + h] = macc[c4][r];   // [s][h]
    }
  }
}

// ---------------------------------------------------------------------------
// K4a: exclusive prefix of Mc within each group of GSZ chunks; totals -> Gs.
// ---------------------------------------------------------------------------
__global__ __launch_bounds__(256) void k4a_prefix_local(
    float* __restrict__ Mc, float* __restrict__ Gs)
{
  const int tid = blockIdx.x * 256 + threadIdx.x;   // 131072
  const int b = tid >> 16;
  const int g = (tid >> 12) & (NGRP - 1);
  const int hs = tid & 4095;
  float run = 0.f;
#pragma unroll
  for (int i = 0; i < GSZ; ++i) {
    const size_t idx = ((size_t)(b * NCHUNK + g * GSZ + i)) * 4096 + hs;
    const float v = Mc[idx];
    Mc[idx] = run;
    run += v;
  }
  Gs[((size_t)(b * NGRP + g)) * 4096 + hs] = run;
}

// ---------------------------------------------------------------------------
// K4b: exclusive prefix over the NGRP group totals (in-place).
// ---------------------------------------------------------------------------
__global__ __launch_bounds__(256) void k4b_prefix_groups(float* __restrict__ Gs)
{
  const int tid = blockIdx.x * 256 + threadIdx.x;   // 8192
  const int b = tid >> 12;
  const int hs = tid & 4095;
  float run = 0.f;
#pragma unroll
  for (int g = 0; g < NGRP; ++g) {
    const size_t idx = ((size_t)(b * NGRP + g)) * 4096 + hs;
    const float v = Gs[idx];
    Gs[idx] = run;
    run += v;
  }
}

// ---------------------------------------------------------------------------
// K56: T recomputed in-block; y = T@U + C@Hseed (MFMA); gate in registers;
// gated y -> bf16 yb tile; out-GEMM (b128 A-frags) + residual + LN.
// 256 thr / 4 waves; LDS union 53.4 KB + sdbc -> 2 blocks/CU.
// ---------------------------------------------------------------------------
__global__ __launch_bounds__(256) void k56_scan_out_ln(
    const bf16* __restrict__ xib, const bf16* __restrict__ zb,
    const float* __restrict__ dbc, const float* __restrict__ dt_w,
    const float* __restrict__ dt_b, const float* __restrict__ Dv,
    const float* __restrict__ Mc, const float* __restrict__ Gs,
    const bf16* __restrict__ wbout, const float* __restrict__ out_b,
    const float* __restrict__ x, const float* __restrict__ ln_g,
    const float* __restrict__ ln_b, float* __restrict__ out)
{
  __shared__ __align__(16) char un[53376];
  bf16* Ut  = (bf16*)un;                 // [256][UST]  20,480 B
  bf16* Hst = (bf16*)(un + 20480);       // [256][UST]  20,480 B
  bf16* Ctl = (bf16*)(un + 40960);       // [32][UST]    2,560 B
  bf16* Tt  = (bf16*)(un + 43520);       // [32][32]     2,048 B
  bf16* yb  = (bf16*)un;                 // phase3: [32][264] 16,896 B
  float* pt = (float*)(un + 20480);      // phase4: [32][PST] 32,896 B
  __shared__ float sdbc[32][33];

  const int tid = threadIdx.x;
  const int wave = tid >> 6, lane = tid & 63, q = lane >> 4, l16 = lane & 15;
  const int cix = blockIdx.x;
  const int R0 = cix * CHUNK;
  const int b = cix >> 8;
  const int cchunk = cix & 255;

  // ---- sdbc load (flat coalesced) ----
  {
    float* sflat = &sdbc[0][0];
    for (int idx = tid; idx < CHUNK * 33; idx += 256)
      sflat[idx] = dbc[(size_t)R0 * 33 + idx];
  }
  __syncthreads();

  // ---- build operand tiles ----
  // T = (C @ B^T) masked (m <= n)  -> Tt
  {
    const int n = tid >> 3;
    const int m0 = (tid & 7) * 4;
    float cn[SD];
#pragma unroll
    for (int s = 0; s < SD; ++s) cn[s] = sdbc[n][17 + s];
    short4v tv;
#pragma unroll
    for (int mm = 0; mm < 4; ++mm) {
      const int m = m0 + mm;
      float t = 0.f;
#pragma unroll
      for (int s = 0; s < SD; ++s) t += cn[s] * sdbc[m][1 + s];
      tv[mm] = (m <= n) ? f2bs(t) : (short)0;
    }
    *(short4v*)((short*)Tt + n * 32 + m0) = tv;
  }
  // Ctl[n][k] = C (k<16) else 0
  {
    const int n = tid >> 3, k0 = (tid & 7) * 4;
    float v[4];
#pragma unroll
    for (int j = 0; j < 4; ++j) {
      const int k = k0 + j;
      v[j] = (k < SD) ? sdbc[n][17 + k] : 0.f;
    }
    *(uint2v*)((short*)Ctl + n * UST + k0) = uint2v{pack2(v[0], v[1]), pack2(v[2], v[3])};
  }
  // Hst[h][s] = seed (s<16) else 0
  {
    const int h = tid;
    const float* mp = Mc + (size_t)cix * 4096 + h;
    const float* gp = Gs + ((size_t)(b * NGRP + cchunk / GSZ)) * 4096 + h;
    unsigned int hp[8];
#pragma unroll
    for (int s2 = 0; s2 < 8; ++s2) {
      const int s = 2 * s2;
      const float v0 = mp[s * HD] + gp[s * HD];
      const float v1 = mp[(s + 1) * HD] + gp[(s + 1) * HD];
      hp[s2] = pack2(v0, v1);
    }
    uint4v* hd = (uint4v*)(Hst + h * UST);
    hd[0] = uint4v{hp[0], hp[1], hp[2], hp[3]};
    hd[1] = uint4v{hp[4], hp[5], hp[6], hp[7]};
    hd[2] = uint4v{0, 0, 0, 0};
    hd[3] = uint4v{0, 0, 0, 0};
  }
  // u -> Ut[h][n]
  {
    const int h = tid;
    const float dtw = dt_w[h], dtb = dt_b[h];
    unsigned int up[16];
#pragma unroll
    for (int n2 = 0; n2 < 16; ++n2) {
      const int n = 2 * n2;
      const float xv0 = b2f(xib[(size_t)(R0 + n) * HD + h]);
      const float xv1 = b2f(xib[(size_t)(R0 + n + 1) * HD + h]);
      const float u0 = xv0 * softplus_f(sdbc[n][0] * dtw + dtb);
      const float u1 = xv1 * softplus_f(sdbc[n + 1][0] * dtw + dtb);
      up[n2] = pack2(u0, u1);
    }
    uint4v* dst = (uint4v*)(Ut + h * UST);
#pragma unroll
    for (int j = 0; j < 4; ++j)
      dst[j] = uint4v{up[4 * j], up[4 * j + 1], up[4 * j + 2], up[4 * j + 3]};
  }
  __syncthreads();

  // ---- y MFMAs: wave -> col-tiles wave*4..wave*4+3, 2 row-tiles ----
  f32x4 acc[2][4] = {};
  {
    bf16x8 aT0 = *(const bf16x8*)(Tt + l16 * 32 + q * 8);
    bf16x8 aT1 = *(const bf16x8*)(Tt + (16 + l16) * 32 + q * 8);
    bf16x8 aC0 = *(const bf16x8*)(Ctl + l16 * UST + q * 8);
    bf16x8 aC1 = *(const bf16x8*)(Ctl + (16 + l16) * UST + q * 8);
#pragma unroll
    for (int c4 = 0; c4 < 4; ++c4) {
      const int ct = wave * 4 + c4;
      bf16x8 bu = *(const bf16x8*)(Ut + (ct * 16 + l16) * UST + q * 8);
      bf16x8 bh = *(const bf16x8*)(Hst + (ct * 16 + l16) * UST + q * 8);
      acc[0][c4] = __builtin_amdgcn_mfma_f32_16x16x32_bf16(aT0, bu, acc[0][c4], 0, 0, 0);
      acc[0][c4] = __builtin_amdgcn_mfma_f32_16x16x32_bf16(aC0, bh, acc[0][c4], 0, 0, 0);
      acc[1][c4] = __builtin_amdgcn_mfma_f32_16x16x32_bf16(aT1, bu, acc[1][c4], 0, 0, 0);
      acc[1][c4] = __builtin_amdgcn_mfma_f32_16x16x32_bf16(aC1, bh, acc[1][c4], 0, 0, 0);
    }
  }
  __syncthreads();   // operand tiles dead; union becomes yb/pt

  // ---- gate in registers: y = (y + D*x_inner) * silu(z) -> yb bf16 ----
  {
#pragma unroll
    for (int c4 = 0; c4 < 4; ++c4) {
      const int h = (wave * 4 + c4) * 16 + l16;
      const float dh = Dv[h];
#pragma unroll
      for (int rt = 0; rt < 2; ++rt)
#pragma unroll
        for (int r = 0; r < 4; ++r) {
          const int n = rt * 16 + q * 4 + r;
          const size_t grow = (size_t)(R0 + n) * HD + h;
          const float xv = b2f(xib[grow]);
          const float zv = b2f(zb[grow]);
          const float yv = acc[rt][c4][r] + dh * xv;
          const float sig = 1.f / (1.f + __expf(-zv));
          ((short*)yb)[n * 264 + h] = f2bs(yv * zv * sig);
        }
    }
  }
  __syncthreads();

  // ---- out GEMM: wave = 32 rows x 64 cols, A-frags via ds_read_b128 ----
  const int cw = wave * 64;
  f32x4 oacc[2][4] = {};
#pragma unroll
  for (int k = 0; k < HD; k += 32) {
    bf16x8 a0 = *(const bf16x8*)(yb + l16 * 264 + k + q * 8);
    bf16x8 a1 = *(const bf16x8*)(yb + (16 + l16) * 264 + k + q * 8);
#pragma unroll
    for (int t = 0; t < 4; ++t) {
      bf16x8 bfr = *(const bf16x8*)(wbout + (size_t)(cw + t * 16 + l16) * HD + k + q * 8);
      oacc[0][t] = __builtin_amdgcn_mfma_f32_16x16x32_bf16(a0, bfr, oacc[0][t], 0, 0, 0);
      oacc[1][t] = __builtin_amdgcn_mfma_f32_16x16x32_bf16(a1, bfr, oacc[1][t], 0, 0, 0);
    }
  }
  // pt = oacc + out_b + residual (pt region disjoint from yb)
#pragma unroll
  for (int t = 0; t < 4; ++t) {
    const int col = cw + t * 16 + l16;
    const float bias = out_b[col];
#pragma unroll
    for (int rt = 0; rt < 2; ++rt)
#pragma unroll
      for (int r = 0; r < 4; ++r) {
        const int row = rt * 16 + q * 4 + r;
        pt[row * PST + col] = oacc[rt][t][r] + bias + x[(size_t)(R0 + row) * HD + col];
      }
  }
  __syncthreads();

  // ---- LayerNorm: wave handles rows wave*8 .. wave*8+7 ----
#pragma unroll
  for (int rr = 0; rr < 8; ++rr) {
    const int row = wave * 8 + rr;
    float p = 0.f;
#pragma unroll
    for (int j = 0; j < 4; ++j) p += pt[row * PST + lane + 64 * j];
#pragma unroll
    for (int off = 32; off > 0; off >>= 1) p += __shfl_xor(p, off);
    const float mu = p * (1.f / 256.f);
    float v2 = 0.f;
#pragma unroll
    for (int j = 0; j < 4; ++j) {
      const float d = pt[row * PST + lane + 64 * j] - mu;
      v2 += d * d;
    }
#pragma unroll
    for (int off = 32; off > 0; off >>= 1) v2 += __shfl_xor(v2, off);
    const float rstd = rsqrtf(v2 * (1.f / 256.f) + LN_EPS);
    const size_t base = (size_t)(R0 + row) * HD;
#pragma unroll
    for (int j = 0; j < 4; ++j) {
      const int cc = lane + 64 * j;
      out[base + cc] = ln_g[cc] * (pt[row * PST + cc] - mu) * rstd + ln_b[cc];
    }
  }
}

// ---------------------------------------------------------------------------
extern "C" void kernel_launch(void* const* d_in, const int* in_sizes, int n_in,
                              void* d_out, int out_size, void* d_ws, size_t ws_size,
                              hipStream_t stream)
{
  const float* x     = (const float*)d_in[0];
  const float* in_w  = (const float*)d_in[1];
  const float* in_b  = (const float*)d_in[2];
  const float* xp_w  = (const float*)d_in[3];
  const float* xp_b  = (const float*)d_in[4];
  const float* dt_w  = (const float*)d_in[5];
  const float* dt_b  = (const float*)d_in[6];
  // d_in[7] = A_log — unused by the reference
  const float* Dv    = (const float*)d_in[8];
  const float* out_w = (const float*)d_in[9];
  const float* out_b = (const float*)d_in[10];
  const float* ln_g  = (const float*)d_in[11];
  const float* ln_b  = (const float*)d_in[12];

  char* ws = (char*)d_ws;
  bf16*  xib   = (bf16*)(ws);               // 8,388,608 B
  bf16*  zb    = (bf16*)(ws +  8388608);    // 8,388,608 B
  bf16*  xb    = (bf16*)(ws + 16777216);    // 8,388,608 B
  float* dbc   = (float*)(ws + 25165824);   // 2,162,688 B
  float* Mc    = (float*)(ws + 27328512);   // 8,388,608 B
  float* Gs    = (float*)(ws + 35717120);   //   524,288 B
  bf16*  wbin  = (bf16*)(ws + 36241408);    //   262,144 B
  bf16*  wbxp  = (bf16*)(ws + 36503552);    //    24,576 B
  bf16*  wbout = (bf16*)(ws + 36528128);    //   131,072 B
  float* out   = (float*)d_out;

  hipLaunchKernelGGL(k0_convert, dim3((NX + NIW + NXP + NOW) / 1024), dim3(256),
                     0, stream, x, in_w, xp_w, out_w, xb, wbin, wbxp, wbout);
  hipLaunchKernelGGL(k1_gemm, dim3(512), dim3(256), 0, stream,
                     xb, wbin, in_b, xib, zb);
  hipLaunchKernelGGL(kS_xp_sum, dim3(BN / CHUNK), dim3(256), 0, stream,
                     xib, wbxp, xp_b, dt_w, dt_b, dbc, Mc);
  hipLaunchKernelGGL(k4a_prefix_local, dim3(NBATCH * NGRP * 4096 / 256),
                     dim3(256), 0, stream, Mc, Gs);
  hipLaunchKernelGGL(k4b_prefix_groups, dim3(NBATCH * 4096 / 256), dim3(256),
                     0, stream, Gs);
  hipLaunchKernelGGL(k56_scan_out_ln, dim3(BN / CHUNK), dim3(256), 0, stream,
                     xib, zb, dbc, dt_w, dt_b, Dv, Mc, Gs,
                     wbout, out_b, x, ln_g, ln_b, out);
}

// Round 10
// 142.100 us; speedup vs baseline: 1.1928x; 1.0076x over previous
//
#include <hip/hip_runtime.h>
#include <hip/hip_bf16.h>

// MambaBlock: H=256, S=16, B=2, N=8192. fp32 I/O.
// No decay (A_log unused) => pure prefix-sum SSM, chunk-parallel.
// Round 10: revert failed cooperative launch (R9 silently no-oped).
// R8 structure + (a) k1 stages A fp32->bf16 in LDS (xb pass eliminated,
// k0 converts weights only), (b) XCD-local k1 block mapping (rt=bid&127)
// so the 4 col-blocks of a row-tile share one XCD's L2 for the A slice.

#define HD 256
#define SD 16
#define NSEQ 8192
#define NBATCH 2
#define BN (NBATCH * NSEQ)      // 16384 rows
#define CHUNK 32
#define NCHUNK (NSEQ / CHUNK)   // 256
#define NGRP 16
#define GSZ (NCHUNK / NGRP)     // 16
#define LN_EPS 1e-5f
#define UST 40                  // bf16 row stride for Ut/Hst/Ctl
#define PST 257                 // f32 row stride for pt

#define NIW (2 * HD * HD)       // 131,072 in_w
#define NXP (48 * HD)           // 12,288  xp_w padded (src 33*256=8448)
#define NOW (HD * HD)           // 65,536  out_w

typedef __hip_bfloat16 bf16;
typedef __attribute__((ext_vector_type(8))) short bf16x8;
typedef __attribute__((ext_vector_type(4))) short short4v;
typedef __attribute__((ext_vector_type(4))) float f32x4;
typedef __attribute__((ext_vector_type(4))) unsigned int uint4v;
typedef __attribute__((ext_vector_type(2))) unsigned int uint2v;

__device__ __forceinline__ float b2f(bf16 v) { return __bfloat162float(v); }
__device__ __forceinline__ short f2bs(float f) {
  union { bf16 b; short s; } u;
  u.b = __float2bfloat16(f);
  return u.s;
}
__device__ __forceinline__ unsigned int pack2(float a, float b) {
  return (unsigned int)(unsigned short)f2bs(a) |
         ((unsigned int)(unsigned short)f2bs(b) << 16);
}
__device__ __forceinline__ bf16x8 cvt_frag(const float* p) {
  bf16x8 r;
#pragma unroll
  for (int j = 0; j < 8; ++j) r[j] = f2bs(p[j]);
  return r;
}
__device__ __forceinline__ float softplus_f(float a) {
  return (a > 20.f) ? a : __logf(1.f + __expf(a));
}

// ---------------------------------------------------------------------------
// K0: weight conversions only: in_w->wbin, xp_w->wbxp (pad 33->48), out_w->wbout
// ---------------------------------------------------------------------------
__global__ __launch_bounds__(256) void k0_weights(
    const float* __restrict__ in_w, const float* __restrict__ xp_w,
    const float* __restrict__ out_w, bf16* __restrict__ wbin,
    bf16* __restrict__ wbxp, bf16* __restrict__ wbout)
{
  const int base = (blockIdx.x * 256 + threadIdx.x) * 4;
  if (base < NIW) {
    f32x4 v = *(const f32x4*)(in_w + base);
    *(short4v*)((short*)wbin + base) =
        short4v{f2bs(v[0]), f2bs(v[1]), f2bs(v[2]), f2bs(v[3])};
  } else if (base < NIW + NXP) {
    const int off = base - NIW;
    short4v s;
    if (off < 33 * HD) {
      f32x4 v = *(const f32x4*)(xp_w + off);
      s = short4v{f2bs(v[0]), f2bs(v[1]), f2bs(v[2]), f2bs(v[3])};
    } else {
      s = short4v{0, 0, 0, 0};
    }
    *(short4v*)((short*)wbxp + off) = s;
  } else if (base < NIW + NXP + NOW) {
    const int off = base - NIW - NXP;
    f32x4 v = *(const f32x4*)(out_w + off);
    *(short4v*)((short*)wbout + off) =
        short4v{f2bs(v[0]), f2bs(v[1]), f2bs(v[2]), f2bs(v[3])};
  }
}

// ---------------------------------------------------------------------------
// K1: tiled GEMM [x_inner|z] = x @ in_w^T + in_b (bf16 out).
// A staged fp32->bf16 into LDS (At aliased with epilogue Ct); B direct from
// global (L2-hot weights). rt = bid&127, ct = bid>>7: the 4 blocks sharing a
// row-tile are bids {r, r+128, r+256, r+384} == same (bid%8) -> same XCD, so
// the A slice is HBM-fetched once and L2-served 3x.
// ---------------------------------------------------------------------------
__global__ __launch_bounds__(256) void k1_gemm(
    const float* __restrict__ x, const bf16* __restrict__ wbin,
    const float* __restrict__ in_b, bf16* __restrict__ xib,
    bf16* __restrict__ zb)
{
  __shared__ __align__(16) char smem[128 * 264 * 2];   // 67,584 B
  bf16* At = (bf16*)smem;        // [128][264] bf16 A-tile (k-major)
  float* Ct = (float*)smem;      // [128][132] f32, aliased after GEMM

  const int tid = threadIdx.x;
  const int rt = blockIdx.x & 127, ct = blockIdx.x >> 7;
  const int R0 = rt * 128, C0 = ct * 128;
  const int wave = tid >> 6, lane = tid & 63, q = lane >> 4, l16 = lane & 15;

  // ---- stage A: 128 rows x 256 k, fp32 -> bf16, coalesced ----
#pragma unroll
  for (int it = 0; it < 16; ++it) {
    const int f = tid + it * 256;           // 128 rows x 32 groups of 8
    const int row = f >> 5, g = f & 31;
    bf16x8 v = cvt_frag(x + (size_t)(R0 + row) * HD + g * 8);
    *(bf16x8*)(At + row * 264 + g * 8) = v;
  }
  __syncthreads();

  // ---- GEMM: wave = 64x64 quadrant; A from LDS, B from global ----
  const int rowHalf = (wave & 1) * 64;
  const int colHalf = (wave >> 1) * 64;
  f32x4 acc[4][4] = {};
  const bf16* bp = wbin + (size_t)(C0 + colHalf + l16) * HD + q * 8;
#pragma unroll
  for (int k = 0; k < HD; k += 32) {
    bf16x8 a[4], b[4];
#pragma unroll
    for (int i = 0; i < 4; ++i)
      a[i] = *(const bf16x8*)(At + (rowHalf + i * 16 + l16) * 264 + k + q * 8);
#pragma unroll
    for (int j = 0; j < 4; ++j)
      b[j] = *(const bf16x8*)(bp + (size_t)j * 16 * HD + k);
#pragma unroll
    for (int i = 0; i < 4; ++i)
#pragma unroll
      for (int j = 0; j < 4; ++j)
        acc[i][j] = __builtin_amdgcn_mfma_f32_16x16x32_bf16(a[i], b[j], acc[i][j], 0, 0, 0);
  }
  __syncthreads();   // At reads complete before Ct overwrite

  // ---- bias + acc -> Ct (C/D: col=l16, row=q*4+r) ----
#pragma unroll
  for (int j = 0; j < 4; ++j) {
    const int col = colHalf + j * 16 + l16;
    const float bias = in_b[C0 + col];
#pragma unroll
    for (int i = 0; i < 4; ++i)
#pragma unroll
      for (int r = 0; r < 4; ++r)
        Ct[(rowHalf + i * 16 + q * 4 + r) * 132 + col] = acc[i][j][r] + bias;
  }
  __syncthreads();

  // ---- coalesced bf16 copy-out ----
  bf16* dst = (C0 < HD) ? xib : zb;
  const int Cd = (C0 < HD) ? C0 : (C0 - HD);
#pragma unroll
  for (int it = 0; it < 8; ++it) {
    const int f = tid + it * 256;           // 128 rows x 16 groups of 8
    const int row = f >> 4, g = f & 15;
    bf16x8 v = cvt_frag(Ct + row * 132 + g * 8);
    *(bf16x8*)(dst + (size_t)(R0 + row) * HD + Cd + g * 8) = v;
  }
}

// ---------------------------------------------------------------------------
// KS: per 32-row chunk: xp-GEMM -> dbc; u = x*softplus(dt) -> Ut[h][n];
// Mc = B^T @ U via MFMA ([s][h] layout).
// ---------------------------------------------------------------------------
__global__ __launch_bounds__(256) void kS_xp_sum(
    const bf16* __restrict__ xib, const bf16* __restrict__ wbxp,
    const float* __restrict__ xp_b, const float* __restrict__ dt_w,
    const float* __restrict__ dt_b, float* __restrict__ dbc,
    float* __restrict__ Mc)
{
  __shared__ __align__(16) bf16 xt[32 * 264];    // 16.9 KB
  __shared__ __align__(16) bf16 wp[48 * 264];    // 25.3 KB
  __shared__ __align__(16) float sdbc[32][33];   // 4.2 KB
  __shared__ __align__(16) bf16 sBt[16 * UST];   // 1.25 KB  [s][n]
  __shared__ __align__(16) bf16 Ut[256 * UST];   // 20 KB    [h][n]
  const int tid = threadIdx.x;
  const int wave = tid >> 6, lane = tid & 63, q = lane >> 4, l16 = lane & 15;
  const int cix = blockIdx.x;
  const int R0 = cix * CHUNK;

#pragma unroll
  for (int it = 0; it < 4; ++it) {
    const int f = tid + it * 256, row = f >> 5, g = f & 31;
    *(bf16x8*)(xt + row * 264 + g * 8) =
        *(const bf16x8*)(xib + (size_t)(R0 + row) * HD + g * 8);
  }
#pragma unroll
  for (int it = 0; it < 6; ++it) {
    const int f = tid + it * 256, row = f >> 5, g = f & 31;
    *(bf16x8*)(wp + row * 264 + g * 8) =
        *(const bf16x8*)(wbxp + (size_t)row * HD + g * 8);
  }
  __syncthreads();

  if (wave < 2) {
    f32x4 pacc[3] = {};
#pragma unroll
    for (int k = 0; k < HD; k += 32) {
      bf16x8 af = *(const bf16x8*)(xt + (wave * 16 + l16) * 264 + k + q * 8);
#pragma unroll
      for (int t = 0; t < 3; ++t) {
        bf16x8 bfr = *(const bf16x8*)(wp + (t * 16 + l16) * 264 + k + q * 8);
        pacc[t] = __builtin_amdgcn_mfma_f32_16x16x32_bf16(af, bfr, pacc[t], 0, 0, 0);
      }
    }
#pragma unroll
    for (int t = 0; t < 3; ++t) {
      const int col = t * 16 + l16;
      if (col < 33) {
        const float bias = xp_b[col];
#pragma unroll
        for (int r = 0; r < 4; ++r) {
          const int row = wave * 16 + q * 4 + r;
          const float v = pacc[t][r] + bias;
          sdbc[row][col] = v;
          if (col >= 1 && col < 17)
            *((short*)sBt + (col - 1) * UST + row) = f2bs(v);
        }
      }
    }
  }
  __syncthreads();

  // dbc flat copy out
  {
    const float* sflat = &sdbc[0][0];
    for (int idx = tid; idx < CHUNK * 33; idx += 256)
      dbc[(size_t)R0 * 33 + idx] = sflat[idx];
  }
  // u -> Ut[h][n]
  {
    const int h = tid;
    const float dtw = dt_w[h], dtb = dt_b[h];
    unsigned int up[16];
#pragma unroll
    for (int n2 = 0; n2 < 16; ++n2) {
      const int n = 2 * n2;
      const float xv0 = b2f(xt[n * 264 + h]);
      const float xv1 = b2f(xt[(n + 1) * 264 + h]);
      const float u0 = xv0 * softplus_f(sdbc[n][0] * dtw + dtb);
      const float u1 = xv1 * softplus_f(sdbc[n + 1][0] * dtw + dtb);
      up[n2] = pack2(u0, u1);
    }
    uint4v* dst = (uint4v*)(Ut + h * UST);
#pragma unroll
    for (int j = 0; j < 4; ++j)
      dst[j] = uint4v{up[4 * j], up[4 * j + 1], up[4 * j + 2], up[4 * j + 3]};
  }
  __syncthreads();

  // Mc = B^T @ U : wave w -> col-tiles w*4..w*4+3
  {
    bf16x8 af = *(const bf16x8*)(sBt + l16 * UST + q * 8);
    f32x4 macc[4] = {};
#pragma unroll
    for (int c4 = 0; c4 < 4; ++c4) {
      const int ct = wave * 4 + c4;
      bf16x8 bu = *(const bf16x8*)(Ut + (ct * 16 + l16) * UST + q * 8);
      macc[c4] = __builtin_amdgcn_mfma_f32_16x16x32_bf16(af, bu, macc[c4], 0, 0, 0);
    }
    float* mbase = Mc + (size_t)cix * 4096;
#pragma unroll
    for (int c4 = 0; c4 < 4; ++c4) {
      const int h = (wave * 4 + c4) * 16 + l16;
#pragma unroll
      for (int r = 0; r < 4; ++r)
        mbase[(q * 4 + r) * HD + h] = macc[c4][r];   // [s][h]
    }
  }
}

// ---------------------------------------------------------------------------
// K4a: exclusive prefix of Mc within each group of GSZ chunks; totals -> Gs.
// ---------------------------------------------------------------------------
__global__ __launch_bounds__(256) void k4a_prefix_local(
    float* __restrict__ Mc, float* __restrict__ Gs)
{
  const int tid = blockIdx.x * 256 + threadIdx.x;   // 131072
  const int b = tid >> 16;
  const int g = (tid >> 12) & (NGRP - 1);
  const int hs = tid & 4095;
  float run = 0.f;
#pragma unroll
  for (int i = 0; i < GSZ; ++i) {
    const size_t idx = ((size_t)(b * NCHUNK + g * GSZ + i)) * 4096 + hs;
    const float v = Mc[idx];
    Mc[idx] = run;
    run += v;
  }
  Gs[((size_t)(b * NGRP + g)) * 4096 + hs] = run;
}

// ---------------------------------------------------------------------------
// K4b: exclusive prefix over the NGRP group totals (in-place).
// ---------------------------------------------------------------------------
__global__ __launch_bounds__(256) void k4b_prefix_groups(float* __restrict__ Gs)
{
  const int tid = blockIdx.x * 256 + threadIdx.x;   // 8192
  const int b = tid >> 12;
  const int hs = tid & 4095;
  float run = 0.f;
#pragma unroll
  for (int g = 0; g < NGRP; ++g) {
    const size_t idx = ((size_t)(b * NGRP + g)) * 4096 + hs;
    const float v = Gs[idx];
    Gs[idx] = run;
    run += v;
  }
}

// ---------------------------------------------------------------------------
// K56: T recomputed in-block; y = T@U + C@Hseed (MFMA); gate in registers;
// gated y -> bf16 yb tile; out-GEMM (b128 A-frags) + residual + LN.
// ---------------------------------------------------------------------------
__global__ __launch_bounds__(256) void k56_scan_out_ln(
    const bf16* __restrict__ xib, const bf16* __restrict__ zb,
    const float* __restrict__ dbc, const float* __restrict__ dt_w,
    const float* __restrict__ dt_b, const float* __restrict__ Dv,
    const float* __restrict__ Mc, const float* __restrict__ Gs,
    const bf16* __restrict__ wbout, const float* __restrict__ out_b,
    const float* __restrict__ x, const float* __restrict__ ln_g,
    const float* __restrict__ ln_b, float* __restrict__ out)
{
  __shared__ __align__(16) char un[53376];
  bf16* Ut  = (bf16*)un;                 // [256][UST]  20,480 B
  bf16* Hst = (bf16*)(un + 20480);       // [256][UST]  20,480 B
  bf16* Ctl = (bf16*)(un + 40960);       // [32][UST]    2,560 B
  bf16* Tt  = (bf16*)(un + 43520);       // [32][32]     2,048 B
  bf16* yb  = (bf16*)un;                 // phase3: [32][264] 16,896 B
  float* pt = (float*)(un + 20480);      // phase4: [32][PST] 32,896 B
  __shared__ float sdbc[32][33];

  const int tid = threadIdx.x;
  const int wave = tid >> 6, lane = tid & 63, q = lane >> 4, l16 = lane & 15;
  const int cix = blockIdx.x;
  const int R0 = cix * CHUNK;
  const int b = cix >> 8;
  const int cchunk = cix & 255;

  // ---- sdbc load (flat coalesced) ----
  {
    float* sflat = &sdbc[0][0];
    for (int idx = tid; idx < CHUNK * 33; idx += 256)
      sflat[idx] = dbc[(size_t)R0 * 33 + idx];
  }
  __syncthreads();

  // ---- build operand tiles ----
  // T = (C @ B^T) masked (m <= n)  -> Tt
  {
    const int n = tid >> 3;
    const int m0 = (tid & 7) * 4;
    float cn[SD];
#pragma unroll
    for (int s = 0; s < SD; ++s) cn[s] = sdbc[n][17 + s];
    short4v tv;
#pragma unroll
    for (int mm = 0; mm < 4; ++mm) {
      const int m = m0 + mm;
      float t = 0.f;
#pragma unroll
      for (int s = 0; s < SD; ++s) t += cn[s] * sdbc[m][1 + s];
      tv[mm] = (m <= n) ? f2bs(t) : (short)0;
    }
    *(short4v*)((short*)Tt + n * 32 + m0) = tv;
  }
  // Ctl[n][k] = C (k<16) else 0
  {
    const int n = tid >> 3, k0 = (tid & 7) * 4;
    float v[4];
#pragma unroll
    for (int j = 0; j < 4; ++j) {
      const int k = k0 + j;
      v[j] = (k < SD) ? sdbc[n][17 + k] : 0.f;
    }
    *(uint2v*)((short*)Ctl + n * UST + k0) = uint2v{pack2(v[0], v[1]), pack2(v[2], v[3])};
  }
  // Hst[h][s] = seed (s<16) else 0
  {
    const int h = tid;
    const float* mp = Mc + (size_t)cix * 4096 + h;
    const float* gp = Gs + ((size_t)(b * NGRP + cchunk / GSZ)) * 4096 + h;
    unsigned int hp[8];
#pragma unroll
    for (int s2 = 0; s2 < 8; ++s2) {
      const int s = 2 * s2;
      hp[s2] = pack2(mp[s * HD] + gp[s * HD], mp[(s + 1) * HD] + gp[(s + 1) * HD]);
    }
    uint4v* hd = (uint4v*)(Hst + h * UST);
    hd[0] = uint4v{hp[0], hp[1], hp[2], hp[3]};
    hd[1] = uint4v{hp[4], hp[5], hp[6], hp[7]};
    hd[2] = uint4v{0, 0, 0, 0};
    hd[3] = uint4v{0, 0, 0, 0};
  }
  // u -> Ut[h][n]
  {
    const int h = tid;
    const float dtw = dt_w[h], dtb = dt_b[h];
    unsigned int up[16];
#pragma unroll
    for (int n2 = 0; n2 < 16; ++n2) {
      const int n = 2 * n2;
      const float xv0 = b2f(xib[(size_t)(R0 + n) * HD + h]);
      const float xv1 = b2f(xib[(size_t)(R0 + n + 1) * HD + h]);
      const float u0 = xv0 * softplus_f(sdbc[n][0] * dtw + dtb);
      const float u1 = xv1 * softplus_f(sdbc[n + 1][0] * dtw + dtb);
      up[n2] = pack2(u0, u1);
    }
    uint4v* dst = (uint4v*)(Ut + h * UST);
#pragma unroll
    for (int j = 0; j < 4; ++j)
      dst[j] = uint4v{up[4 * j], up[4 * j + 1], up[4 * j + 2], up[4 * j + 3]};
  }
  __syncthreads();

  // ---- y MFMAs: wave -> col-tiles wave*4..wave*4+3, 2 row-tiles ----
  f32x4 acc[2][4] = {};
  {
    bf16x8 aT0 = *(const bf16x8*)(Tt + l16 * 32 + q * 8);
    bf16x8 aT1 = *(const bf16x8*)(Tt + (16 + l16) * 32 + q * 8);
    bf16x8 aC0 = *(const bf16x8*)(Ctl + l16 * UST + q * 8);
    bf16x8 aC1 = *(const bf16x8*)(Ctl + (16 + l16) * UST + q * 8);
#pragma unroll
    for (int c4 = 0; c4 < 4; ++c4) {
      const int ct = wave * 4 + c4;
      bf16x8 bu = *(const bf16x8*)(Ut + (ct * 16 + l16) * UST + q * 8);
      bf16x8 bh = *(const bf16x8*)(Hst + (ct * 16 + l16) * UST + q * 8);
      acc[0][c4] = __builtin_amdgcn_mfma_f32_16x16x32_bf16(aT0, bu, acc[0][c4], 0, 0, 0);
      acc[0][c4] = __builtin_amdgcn_mfma_f32_16x16x32_bf16(aC0, bh, acc[0][c4], 0, 0, 0);
      acc[1][c4] = __builtin_amdgcn_mfma_f32_16x16x32_bf16(aT1, bu, acc[1][c4], 0, 0, 0);
      acc[1][c4] = __builtin_amdgcn_mfma_f32_16x16x32_bf16(aC1, bh, acc[1][c4], 0, 0, 0);
    }
  }
  __syncthreads();   // operand tiles dead; union becomes yb/pt

  // ---- gate in registers: y = (y + D*x_inner) * silu(z) -> yb bf16 ----
  {
#pragma unroll
    for (int c4 = 0; c4 < 4; ++c4) {
      const int h = (wave * 4 + c4) * 16 + l16;
      const float dh = Dv[h];
#pragma unroll
      for (int rt = 0; rt < 2; ++rt)
#pragma unroll
        for (int r = 0; r < 4; ++r) {
          const int n = rt * 16 + q * 4 + r;
          const size_t grow = (size_t)(R0 + n) * HD + h;
          const float xv = b2f(xib[grow]);
          const float zv = b2f(zb[grow]);
          const float yv = acc[rt][c4][r] + dh * xv;
          const float sig = 1.f / (1.f + __expf(-zv));
          ((short*)yb)[n * 264 + h] = f2bs(yv * zv * sig);
        }
    }
  }
  __syncthreads();

  // ---- out GEMM: wave = 32 rows x 64 cols, A-frags via ds_read_b128 ----
  const int cw = wave * 64;
  f32x4 oacc[2][4] = {};
#pragma unroll
  for (int k = 0; k < HD; k += 32) {
    bf16x8 a0 = *(const bf16x8*)(yb + l16 * 264 + k + q * 8);
    bf16x8 a1 = *(const bf16x8*)(yb + (16 + l16) * 264 + k + q * 8);
#pragma unroll
    for (int t = 0; t < 4; ++t) {
      bf16x8 bfr = *(const bf16x8*)(wbout + (size_t)(cw + t * 16 + l16) * HD + k + q * 8);
      oacc[0][t] = __builtin_amdgcn_mfma_f32_16x16x32_bf16(a0, bfr, oacc[0][t], 0, 0, 0);
      oacc[1][t] = __builtin_amdgcn_mfma_f32_16x16x32_bf16(a1, bfr, oacc[1][t], 0, 0, 0);
    }
  }
  // pt = oacc + out_b + residual (pt region disjoint from yb)
#pragma unroll
  for (int t = 0; t < 4; ++t) {
    const int col = cw + t * 16 + l16;
    const float bias = out_b[col];
#pragma unroll
    for (int rt = 0; rt < 2; ++rt)
#pragma unroll
      for (int r = 0; r < 4; ++r) {
        const int row = rt * 16 + q * 4 + r;
        pt[row * PST + col] = oacc[rt][t][r] + bias + x[(size_t)(R0 + row) * HD + col];
      }
  }
  __syncthreads();

  // ---- LayerNorm: wave handles rows wave*8 .. wave*8+7 ----
#pragma unroll
  for (int rr = 0; rr < 8; ++rr) {
    const int row = wave * 8 + rr;
    float p = 0.f;
#pragma unroll
    for (int j = 0; j < 4; ++j) p += pt[row * PST + lane + 64 * j];
#pragma unroll
    for (int off = 32; off > 0; off >>= 1) p += __shfl_xor(p, off);
    const float mu = p * (1.f / 256.f);
    float v2 = 0.f;
#pragma unroll
    for (int j = 0; j < 4; ++j) {
      const float d = pt[row * PST + lane + 64 * j] - mu;
      v2 += d * d;
    }
#pragma unroll
    for (int off = 32; off > 0; off >>= 1) v2 += __shfl_xor(v2, off);
    const float rstd = rsqrtf(v2 * (1.f / 256.f) + LN_EPS);
    const size_t base = (size_t)(R0 + row) * HD;
#pragma unroll
    for (int j = 0; j < 4; ++j) {
      const int cc = lane + 64 * j;
      out[base + cc] = ln_g[cc] * (pt[row * PST + cc] - mu) * rstd + ln_b[cc];
    }
  }
}

// ---------------------------------------------------------------------------
extern "C" void kernel_launch(void* const* d_in, const int* in_sizes, int n_in,
                              void* d_out, int out_size, void* d_ws, size_t ws_size,
                              hipStream_t stream)
{
  const float* x     = (const float*)d_in[0];
  const float* in_w  = (const float*)d_in[1];
  const float* in_b  = (const float*)d_in[2];
  const float* xp_w  = (const float*)d_in[3];
  const float* xp_b  = (const float*)d_in[4];
  const float* dt_w  = (const float*)d_in[5];
  const float* dt_b  = (const float*)d_in[6];
  // d_in[7] = A_log — unused by the reference
  const float* Dv    = (const float*)d_in[8];
  const float* out_w = (const float*)d_in[9];
  const float* out_b = (const float*)d_in[10];
  const float* ln_g  = (const float*)d_in[11];
  const float* ln_b  = (const float*)d_in[12];

  char* ws = (char*)d_ws;
  bf16*  xib   = (bf16*)(ws);               // 8,388,608 B
  bf16*  zb    = (bf16*)(ws +  8388608);    // 8,388,608 B
  float* dbc   = (float*)(ws + 16777216);   // 2,162,688 B
  float* Mc    = (float*)(ws + 18939904);   // 8,388,608 B
  float* Gs    = (float*)(ws + 27328512);   //   524,288 B
  bf16*  wbin  = (bf16*)(ws + 27852800);    //   262,144 B
  bf16*  wbxp  = (bf16*)(ws + 28114944);    //    24,576 B
  bf16*  wbout = (bf16*)(ws + 28139520);    //   131,072 B
  float* out   = (float*)d_out;

  hipLaunchKernelGGL(k0_weights, dim3((NIW + NXP + NOW) / 1024), dim3(256),
                     0, stream, in_w, xp_w, out_w, wbin, wbxp, wbout);
  hipLaunchKernelGGL(k1_gemm, dim3(512), dim3(256), 0, stream,
                     x, wbin, in_b, xib, zb);
  hipLaunchKernelGGL(kS_xp_sum, dim3(BN / CHUNK), dim3(256), 0, stream,
                     xib, wbxp, xp_b, dt_w, dt_b, dbc, Mc);
  hipLaunchKernelGGL(k4a_prefix_local, dim3(NBATCH * NGRP * 4096 / 256),
                     dim3(256), 0, stream, Mc, Gs);
  hipLaunchKernelGGL(k4b_prefix_groups, dim3(NBATCH * 4096 / 256), dim3(256),
                     0, stream, Gs);
  hipLaunchKernelGGL(k56_scan_out_ln, dim3(BN / CHUNK), dim3(256), 0, stream,
                     xib, zb, dbc, dt_w, dt_b, Dv, Mc, Gs,
                     wbout, out_b, x, ln_g, ln_b, out);
}